// Round 1
// baseline (469.181 us; speedup 1.0000x reference)
//
#include <hip/hip_runtime.h>
#include <hip/hip_bf16.h>

// SpatialRelation on MI355X.
// Key restructure: A@(E·W^t) = (A@E)·W^t  => big einsum done ONCE, edges done
// as a single E0@W^3 GEMM. All GEMMs are bf16 MFMA 16x16x32, fp32 accumulate.

typedef unsigned short u16;
typedef __attribute__((ext_vector_type(4))) float f32x4;
typedef __attribute__((ext_vector_type(8))) short bf16x8;

#define DI static __device__ __forceinline__

DI u16 f2bf(float f) {
    unsigned u = __builtin_bit_cast(unsigned, f);
    return (u16)((u + 0x7fffu + ((u >> 16) & 1u)) >> 16);  // RNE
}
DI float bf2f(u16 h) { return __builtin_bit_cast(float, ((unsigned)h) << 16); }

DI void cvt_store8(u16* dst, float4 a, float4 b) {
    u16 tmp[8] = {f2bf(a.x), f2bf(a.y), f2bf(a.z), f2bf(a.w),
                  f2bf(b.x), f2bf(b.y), f2bf(b.z), f2bf(b.w)};
    *(uint4*)dst = *(const uint4*)tmp;
}

// B-operand image layout (per 32-wide K chunk): ((kc*128+n)*4 + (g ^ ((n>>1)&3)))*8 + o
// where k = kc*32 + g*8 + o. Gives conflict-free ds_read_b128 B-fragments.
DI int imgIdx(int k, int n) {
    return (((k >> 5) * 128 + n) * 4 + (((k >> 3) & 3) ^ ((n >> 1) & 3))) * 8 + (k & 7);
}

// B fragment read from a staged 4KB-chunk (4096 shorts) in LDS
DI bf16x8 wfrag(const u16* sw, int tt, int l15, int quad) {
    return *(const bf16x8*)&sw[(((tt * 16 + l15) * 4) + (quad ^ ((l15 >> 1) & 3))) * 8];
}

#define MFMA16(a, b, c) __builtin_amdgcn_mfma_f32_16x16x32_bf16(a, b, c, 0, 0, 0)

// ---------------------------------------------------------------- prep 1
// blocks 0-7: W2 = linkW @ linkW (fp32).  blocks 8+: bf16 weight images.
__global__ __launch_bounds__(256) void k_prep1(
    const float* __restrict__ linkW, const float* __restrict__ resetW,
    const float* __restrict__ updateW, const float* __restrict__ transW,
    const float* __restrict__ attW1, const float* __restrict__ outW,
    float* __restrict__ W2, u16* __restrict__ linkImg, u16* __restrict__ WrImg,
    u16* __restrict__ WzImg, u16* __restrict__ WhImg, u16* __restrict__ attW1Img,
    u16* __restrict__ outWImg)
{
    int blk = blockIdx.x, t = threadIdx.x;
    if (blk < 8) {
        int r0 = blk * 16;
        for (int i = 0; i < 8; i++) {
            int idx = t + i * 256;
            int r = r0 + (idx >> 7), c = idx & 127;
            float acc = 0.f;
            for (int k = 0; k < 128; k++) acc += linkW[r * 128 + k] * linkW[k * 128 + c];
            W2[r * 128 + c] = acc;
        }
    } else {
        const float* src; u16* dst; int base;
        if (blk < 12)      { src = resetW;  dst = WrImg;    base = 8; }
        else if (blk < 16) { src = updateW; dst = WzImg;    base = 12; }
        else if (blk < 20) { src = transW;  dst = WhImg;    base = 16; }
        else if (blk < 22) { src = linkW;   dst = linkImg;  base = 20; }
        else if (blk < 24) { src = attW1;   dst = attW1Img; base = 22; }
        else if (blk < 26) { src = outW;    dst = outWImg;  base = 24; }
        else return;
        int off = (blk - base) * 8192;
        for (int i = 0; i < 32; i++) {
            int e = off + t + i * 256;
            int k = e >> 7, n = e & 127;
            dst[imgIdx(k, n)] = f2bf(src[e]);
        }
    }
}

// ---------------------------------------------------------------- prep 2
// blocks 0-7: W3 = W2 @ linkW -> bf16 image.  block 8: ebias = b(W2+W+I).
__global__ __launch_bounds__(256) void k_prep2(
    const float* __restrict__ linkW, const float* __restrict__ linkb,
    const float* __restrict__ W2, u16* __restrict__ W3Img, float* __restrict__ ebias)
{
    int blk = blockIdx.x, t = threadIdx.x;
    if (blk < 8) {
        int r0 = blk * 16;
        for (int i = 0; i < 8; i++) {
            int idx = t + i * 256;
            int r = r0 + (idx >> 7), c = idx & 127;
            float acc = 0.f;
            for (int k = 0; k < 128; k++) acc += W2[r * 128 + k] * linkW[k * 128 + c];
            W3Img[imgIdx(r, c)] = f2bf(acc);
        }
    } else if (t < 128) {
        float acc = linkb[t];
        for (int k = 0; k < 128; k++) acc += linkb[k] * (W2[k * 128 + t] + linkW[k * 128 + t]);
        ebias[t] = acc;
    }
}

// ---------------------------------------------------------------- E transpose
// E0 fp32 [B][2048][128] -> bf16 B-operand image; also edge column-sums for residual.
__global__ __launch_bounds__(256) void k_te(
    const float* __restrict__ E0, u16* __restrict__ Eswz, float* __restrict__ resid)
{
    __shared__ alignas(16) u16 sT[4096];
    __shared__ float sCol[128];
    int t = threadIdx.x, kc = blockIdx.x, b = blockIdx.y;
    const float* Eb = E0 + (size_t)b * 262144 + (size_t)kc * 32 * 128;
    if (t < 128) sCol[t] = 0.f;
    float part[4] = {0.f, 0.f, 0.f, 0.f};
    int ncol = (t & 31) * 4;
    for (int i = 0; i < 4; i++) {
        int f4i = t + i * 256;
        int k5 = f4i >> 5;
        float4 v = *(const float4*)&Eb[k5 * 128 + ncol];
        int g = k5 >> 3, o = k5 & 7;
        float vv[4] = {v.x, v.y, v.z, v.w};
#pragma unroll
        for (int j = 0; j < 4; j++) {
            int n = ncol + j;
            sT[(n * 4 + (g ^ ((n >> 1) & 3))) * 8 + o] = f2bf(vv[j]);
            part[j] += vv[j];
        }
    }
    __syncthreads();
#pragma unroll
    for (int j = 0; j < 4; j++) atomicAdd(&sCol[ncol + j], part[j]);
    u16* dst = Eswz + (size_t)b * 262144 + (size_t)kc * 4096;
    ((uint4*)dst)[t] = ((const uint4*)sT)[t];
    ((uint4*)dst)[t + 256] = ((const uint4*)sT)[t + 256];
    __syncthreads();
    if (t < 128) atomicAdd(&resid[b * 128 + t], sCol[t]);
}

// ---------------------------------------------------------------- G0 = A @ E0
// Also computes rowsum(A) (for the link-bias recurrence term).
__global__ __launch_bounds__(256) void k_g0(
    const float* __restrict__ A, const u16* __restrict__ Eswz,
    u16* __restrict__ aOut, float* __restrict__ rowsum)
{
    __shared__ alignas(16) u16 sA[2][64 * 40];
    __shared__ alignas(16) u16 sB[2][4096];
    __shared__ float sRed[256];
    int t = threadIdx.x, lane = t & 63, wid = t >> 6, l15 = lane & 15, quad = lane >> 4;
    int mBase = wid * 16;
    int b = blockIdx.y, n0 = blockIdx.x * 64;
    const float* Ab = A + ((size_t)(b * 512 + n0)) * 2048;
    const u16* Eb = Eswz + (size_t)b * 262144;
    int arow = t >> 2, aco = (t & 3) * 8;
    float rsum = 0.f;
    float4 pa0, pa1; uint4 pb0, pb1;

    pa0 = *(const float4*)&Ab[(size_t)arow * 2048 + aco];
    pa1 = *(const float4*)&Ab[(size_t)arow * 2048 + aco + 4];
    { const uint4* s = (const uint4*)Eb; pb0 = s[t]; pb1 = s[t + 256]; }
    rsum += pa0.x + pa0.y + pa0.z + pa0.w + pa1.x + pa1.y + pa1.z + pa1.w;
    cvt_store8(&sA[0][arow * 40 + aco], pa0, pa1);
    ((uint4*)sB[0])[t] = pb0; ((uint4*)sB[0])[t + 256] = pb1;
    __syncthreads();

    f32x4 zero4 = {0.f, 0.f, 0.f, 0.f};
    f32x4 acc[8];
#pragma unroll
    for (int i = 0; i < 8; i++) acc[i] = zero4;

    for (int kc = 0; kc < 64; kc++) {
        int cur = kc & 1, nxt = cur ^ 1;
        if (kc < 63) {
            pa0 = *(const float4*)&Ab[(size_t)arow * 2048 + (kc + 1) * 32 + aco];
            pa1 = *(const float4*)&Ab[(size_t)arow * 2048 + (kc + 1) * 32 + aco + 4];
            const uint4* s = (const uint4*)(Eb + (size_t)(kc + 1) * 4096);
            pb0 = s[t]; pb1 = s[t + 256];
        }
        bf16x8 af = *(const bf16x8*)&sA[cur][(mBase + l15) * 40 + quad * 8];
#pragma unroll
        for (int tt = 0; tt < 8; tt++) {
            bf16x8 bf = wfrag(sB[cur], tt, l15, quad);
            acc[tt] = MFMA16(af, bf, acc[tt]);
        }
        if (kc < 63) {
            rsum += pa0.x + pa0.y + pa0.z + pa0.w + pa1.x + pa1.y + pa1.z + pa1.w;
            cvt_store8(&sA[nxt][arow * 40 + aco], pa0, pa1);
            ((uint4*)sB[nxt])[t] = pb0; ((uint4*)sB[nxt])[t + 256] = pb1;
        }
        __syncthreads();
    }
    sRed[arow * 4 + (t & 3)] = rsum;
    __syncthreads();
    if (t < 64)
        rowsum[(size_t)(b * 512 + n0) + t] =
            sRed[t * 4] + sRed[t * 4 + 1] + sRed[t * 4 + 2] + sRed[t * 4 + 3];
    size_t gR0 = (size_t)(b * 512 + n0);
#pragma unroll
    for (int tt = 0; tt < 8; tt++) {
        int col = tt * 16 + l15;
#pragma unroll
        for (int r = 0; r < 4; r++)
            aOut[(gR0 + mBase + quad * 4 + r) * 128 + col] = f2bf(acc[tt][r]);
    }
}

// ---------------------------------------------------------------- per-step fused GRU
// a_new = a_prev@linkW + rowsum*link_b ; r,z = sigmoid([a,p]@W) ; h = tanh([a,r*p]@W)
// p_new = (1-z)p + z h.  z/r/h never leave the block.
__global__ __launch_bounds__(256) void k_gates(
    u16* __restrict__ aBuf, const float* __restrict__ pIn, float* __restrict__ pOut,
    const u16* __restrict__ pBfIn, u16* __restrict__ pBfOut, int first,
    const float* __restrict__ rowsum,
    const u16* __restrict__ linkImg, const u16* __restrict__ WrImg,
    const u16* __restrict__ WzImg, const u16* __restrict__ WhImg,
    const float* __restrict__ link_b, const float* __restrict__ reset_b,
    const float* __restrict__ update_b, const float* __restrict__ trans_b)
{
    __shared__ alignas(16) u16 sA[64 * 136];
    __shared__ alignas(16) u16 sP[64 * 136];
    __shared__ alignas(16) u16 sW[2][4096];
    int t = threadIdx.x, lane = t & 63, wid = t >> 6, l15 = lane & 15, quad = lane >> 4;
    int mBase = wid * 16;
    size_t gR0 = (size_t)blockIdx.x * 64;

    for (int i = 0; i < 4; i++) {
        int s8 = t + i * 256; int row = s8 >> 4, colk = (s8 & 15) * 8;
        *(uint4*)&sA[row * 136 + colk] = *(const uint4*)&aBuf[(gR0 + row) * 128 + colk];
    }
    if (first) {
        for (int i = 0; i < 4; i++) {
            int s8 = t + i * 256; int row = s8 >> 4, colk = (s8 & 15) * 8;
            float4 a = *(const float4*)&pIn[(gR0 + row) * 128 + colk];
            float4 b = *(const float4*)&pIn[(gR0 + row) * 128 + colk + 4];
            cvt_store8(&sP[row * 136 + colk], a, b);
        }
    } else {
        for (int i = 0; i < 4; i++) {
            int s8 = t + i * 256; int row = s8 >> 4, colk = (s8 & 15) * 8;
            *(uint4*)&sP[row * 136 + colk] = *(const uint4*)&pBfIn[(gR0 + row) * 128 + colk];
        }
    }
    __syncthreads();

    f32x4 zero4 = {0.f, 0.f, 0.f, 0.f};
    f32x4 acc[8];
#pragma unroll
    for (int i = 0; i < 8; i++) acc[i] = zero4;

    // ---- a_new
    for (int kc = 0; kc < 4; kc++) {
        ((uint4*)sW[0])[t] = ((const uint4*)(linkImg + kc * 4096))[t];
        ((uint4*)sW[0])[t + 256] = ((const uint4*)(linkImg + kc * 4096))[t + 256];
        __syncthreads();
        bf16x8 af = *(const bf16x8*)&sA[(mBase + l15) * 136 + kc * 32 + quad * 8];
#pragma unroll
        for (int tt = 0; tt < 8; tt++) acc[tt] = MFMA16(af, wfrag(sW[0], tt, l15, quad), acc[tt]);
        __syncthreads();
    }
    float sv[4];
#pragma unroll
    for (int r = 0; r < 4; r++) sv[r] = rowsum[gR0 + mBase + quad * 4 + r];
#pragma unroll
    for (int tt = 0; tt < 8; tt++) {
        int col = tt * 16 + l15; float lb = link_b[col];
#pragma unroll
        for (int r = 0; r < 4; r++)
            sA[(mBase + quad * 4 + r) * 136 + col] = f2bf(acc[tt][r] + sv[r] * lb);
    }
    __syncthreads();
    for (int i = 0; i < 4; i++) {
        int s8 = t + i * 256; int row = s8 >> 4, colk = (s8 & 15) * 8;
        *(uint4*)&aBuf[(gR0 + row) * 128 + colk] = *(const uint4*)&sA[row * 136 + colk];
    }

    // ---- r, z (shared A fragments)
    f32x4 aR[8], aZ[8];
#pragma unroll
    for (int i = 0; i < 8; i++) { aR[i] = zero4; aZ[i] = zero4; }
    for (int kc = 0; kc < 8; kc++) {
        ((uint4*)sW[0])[t] = ((const uint4*)(WrImg + kc * 4096))[t];
        ((uint4*)sW[0])[t + 256] = ((const uint4*)(WrImg + kc * 4096))[t + 256];
        ((uint4*)sW[1])[t] = ((const uint4*)(WzImg + kc * 4096))[t];
        ((uint4*)sW[1])[t + 256] = ((const uint4*)(WzImg + kc * 4096))[t + 256];
        __syncthreads();
        const u16* aSrc = (kc < 4) ? sA : sP;
        int kk = (kc & 3) * 32;
        bf16x8 af = *(const bf16x8*)&aSrc[(mBase + l15) * 136 + kk + quad * 8];
#pragma unroll
        for (int tt = 0; tt < 8; tt++) {
            aR[tt] = MFMA16(af, wfrag(sW[0], tt, l15, quad), aR[tt]);
            aZ[tt] = MFMA16(af, wfrag(sW[1], tt, l15, quad), aZ[tt]);
        }
        __syncthreads();
    }
    // sigmoid; rp = r*p overwrites sP (wave-local rows only)
#pragma unroll
    for (int tt = 0; tt < 8; tt++) {
        int col = tt * 16 + l15; float rb = reset_b[col], ub = update_b[col];
#pragma unroll
        for (int r = 0; r < 4; r++) {
            int row = mBase + quad * 4 + r;
            float rv = 1.f / (1.f + __expf(-(aR[tt][r] + rb)));
            float zv = 1.f / (1.f + __expf(-(aZ[tt][r] + ub)));
            aZ[tt][r] = zv;
            float p = bf2f(sP[row * 136 + col]);
            sP[row * 136 + col] = f2bf(rv * p);
        }
    }
    // ---- h
#pragma unroll
    for (int i = 0; i < 8; i++) aR[i] = zero4;
    for (int kc = 0; kc < 8; kc++) {
        ((uint4*)sW[0])[t] = ((const uint4*)(WhImg + kc * 4096))[t];
        ((uint4*)sW[0])[t + 256] = ((const uint4*)(WhImg + kc * 4096))[t + 256];
        __syncthreads();
        const u16* aSrc = (kc < 4) ? sA : sP;
        int kk = (kc & 3) * 32;
        bf16x8 af = *(const bf16x8*)&aSrc[(mBase + l15) * 136 + kk + quad * 8];
#pragma unroll
        for (int tt = 0; tt < 8; tt++) aR[tt] = MFMA16(af, wfrag(sW[0], tt, l15, quad), aR[tt]);
        __syncthreads();
    }
    // ---- GRU update (fp32 prop path)
#pragma unroll
    for (int tt = 0; tt < 8; tt++) {
        int col = tt * 16 + l15; float tb = trans_b[col];
#pragma unroll
        for (int r = 0; r < 4; r++) {
            size_t row = gR0 + mBase + quad * 4 + r;
            float h = tanhf(aR[tt][r] + tb);
            float z = aZ[tt][r];
            float p = pIn[row * 128 + col];
            float pn = (1.f - z) * p + z * h;
            pOut[row * 128 + col] = pn;
            pBfOut[row * 128 + col] = f2bf(pn);
        }
    }
}

// ---------------------------------------------------------------- attention + out
__global__ __launch_bounds__(256) void k_att(
    const u16* __restrict__ pBf, const u16* __restrict__ attW1Img,
    const u16* __restrict__ outWImg, const float* __restrict__ att_b1,
    const float* __restrict__ att_W2, const float* __restrict__ att_b2,
    const float* __restrict__ out_b, float* __restrict__ atten, float* __restrict__ outPool)
{
    __shared__ alignas(16) u16 sP[64 * 136];
    __shared__ alignas(16) u16 sW[2][4096];
    int t = threadIdx.x, lane = t & 63, wid = t >> 6, l15 = lane & 15, quad = lane >> 4;
    int mBase = wid * 16;
    size_t gR0 = (size_t)blockIdx.x * 64;
    for (int i = 0; i < 4; i++) {
        int s8 = t + i * 256; int row = s8 >> 4, colk = (s8 & 15) * 8;
        *(uint4*)&sP[row * 136 + colk] = *(const uint4*)&pBf[(gR0 + row) * 128 + colk];
    }
    __syncthreads();
    f32x4 zero4 = {0.f, 0.f, 0.f, 0.f};
    f32x4 aA[8], aO[8];
#pragma unroll
    for (int i = 0; i < 8; i++) { aA[i] = zero4; aO[i] = zero4; }
    for (int kc = 0; kc < 4; kc++) {
        ((uint4*)sW[0])[t] = ((const uint4*)(attW1Img + kc * 4096))[t];
        ((uint4*)sW[0])[t + 256] = ((const uint4*)(attW1Img + kc * 4096))[t + 256];
        ((uint4*)sW[1])[t] = ((const uint4*)(outWImg + kc * 4096))[t];
        ((uint4*)sW[1])[t + 256] = ((const uint4*)(outWImg + kc * 4096))[t + 256];
        __syncthreads();
        bf16x8 af = *(const bf16x8*)&sP[(mBase + l15) * 136 + kc * 32 + quad * 8];
#pragma unroll
        for (int tt = 0; tt < 8; tt++) {
            aA[tt] = MFMA16(af, wfrag(sW[0], tt, l15, quad), aA[tt]);
            aO[tt] = MFMA16(af, wfrag(sW[1], tt, l15, quad), aO[tt]);
        }
        __syncthreads();
    }
    float part[4] = {0.f, 0.f, 0.f, 0.f};
#pragma unroll
    for (int tt = 0; tt < 8; tt++) {
        int col = tt * 16 + l15;
        float b1 = att_b1[col], w2 = att_W2[col], ob = out_b[col];
#pragma unroll
        for (int r = 0; r < 4; r++) {
            part[r] += tanhf(aA[tt][r] + b1) * w2;
            outPool[(gR0 + mBase + quad * 4 + r) * 128 + col] = tanhf(aO[tt][r] + ob);
        }
    }
    float b2 = att_b2[0];
#pragma unroll
    for (int r = 0; r < 4; r++) {
        float loc = part[r];
        loc += __shfl_xor(loc, 1); loc += __shfl_xor(loc, 2);
        loc += __shfl_xor(loc, 4); loc += __shfl_xor(loc, 8);
        if (l15 == 0) atten[gR0 + mBase + quad * 4 + r] = loc + b2;
    }
}

// ---------------------------------------------------------------- edges out: E0@W3 + ebias
__global__ __launch_bounds__(256) void k_eout(
    const float* __restrict__ E0, const u16* __restrict__ W3Img,
    const float* __restrict__ ebias, float* __restrict__ Eout)
{
    __shared__ alignas(16) u16 sE[64 * 136];
    __shared__ alignas(16) u16 sW[4096];
    int t = threadIdx.x, lane = t & 63, wid = t >> 6, l15 = lane & 15, quad = lane >> 4;
    int mBase = wid * 16;
    int b = blockIdx.y, e0 = blockIdx.x * 64;
    const float* Eb = E0 + ((size_t)b * 2048 + e0) * 128;
    for (int i = 0; i < 4; i++) {
        int s8 = t + i * 256; int row = s8 >> 4, colk = (s8 & 15) * 8;
        float4 a = *(const float4*)&Eb[(size_t)row * 128 + colk];
        float4 b4 = *(const float4*)&Eb[(size_t)row * 128 + colk + 4];
        cvt_store8(&sE[row * 136 + colk], a, b4);
    }
    __syncthreads();
    f32x4 zero4 = {0.f, 0.f, 0.f, 0.f};
    f32x4 acc[8];
#pragma unroll
    for (int i = 0; i < 8; i++) acc[i] = zero4;
    for (int kc = 0; kc < 4; kc++) {
        ((uint4*)sW)[t] = ((const uint4*)(W3Img + kc * 4096))[t];
        ((uint4*)sW)[t + 256] = ((const uint4*)(W3Img + kc * 4096))[t + 256];
        __syncthreads();
        bf16x8 af = *(const bf16x8*)&sE[(mBase + l15) * 136 + kc * 32 + quad * 8];
#pragma unroll
        for (int tt = 0; tt < 8; tt++) acc[tt] = MFMA16(af, wfrag(sW, tt, l15, quad), acc[tt]);
        __syncthreads();
    }
    float* Ob = Eout + ((size_t)b * 2048 + e0) * 128;
#pragma unroll
    for (int tt = 0; tt < 8; tt++) {
        int col = tt * 16 + l15; float eb = ebias[col];
#pragma unroll
        for (int r = 0; r < 4; r++)
            Ob[(size_t)(mBase + quad * 4 + r) * 128 + col] = acc[tt][r] + eb;
    }
}

// ---------------------------------------------------------------- softmax-pool + residual
__global__ __launch_bounds__(256) void k_fin(
    const float* __restrict__ atten, const float* __restrict__ outPool,
    const float* __restrict__ prop0, const float* __restrict__ resid,
    float* __restrict__ outRes, float* __restrict__ outMul)
{
    __shared__ float swv[512];
    __shared__ float sred[256];
    int t = threadIdx.x, b = blockIdx.x;
    float a0 = atten[b * 512 + t], a1 = atten[b * 512 + 256 + t];
    sred[t] = fmaxf(a0, a1); __syncthreads();
    for (int s = 128; s > 0; s >>= 1) { if (t < s) sred[t] = fmaxf(sred[t], sred[t + s]); __syncthreads(); }
    float mx = sred[0]; __syncthreads();
    float e0 = __expf(a0 - mx), e1 = __expf(a1 - mx);
    swv[t] = e0; swv[t + 256] = e1;
    sred[t] = e0 + e1; __syncthreads();
    for (int s = 128; s > 0; s >>= 1) { if (t < s) sred[t] += sred[t + s]; __syncthreads(); }
    float Z = sred[0]; __syncthreads();
    int col = t & 127, half = t >> 7;
    const float* op = outPool + ((size_t)b * 512 + half * 256) * 128 + col;
    const float* pp = prop0 + ((size_t)b * 512 + half * 256) * 128 + col;
    float accM = 0.f, accN = 0.f;
    for (int n = 0; n < 256; n++) {
        accM += swv[half * 256 + n] * op[(size_t)n * 128];
        accN += pp[(size_t)n * 128];
    }
    sred[t] = accM; __syncthreads();
    float mulv = 0.f;
    if (t < 128) mulv = (sred[t] + sred[t + 128]) / Z;
    __syncthreads();
    sred[t] = accN; __syncthreads();
    if (t < 128) {
        float nodesum = sred[t] + sred[t + 128];
        float rv = (nodesum + resid[b * 128 + t]) * (1.f / 2560.f);
        outMul[b * 128 + t] = mulv;
        outRes[b * 128 + t] = fmaxf(0.f, tanhf(mulv) + rv);
    }
}

// ================================================================ launch
extern "C" void kernel_launch(void* const* d_in, const int* in_sizes, int n_in,
                              void* d_out, int out_size, void* d_ws, size_t ws_size,
                              hipStream_t stream)
{
    const float* prop0  = (const float*)d_in[0];
    const float* edge0  = (const float*)d_in[1];
    const float* Amat   = (const float*)d_in[2];
    const float* linkW  = (const float*)d_in[4];
    const float* linkb  = (const float*)d_in[5];
    const float* resetW = (const float*)d_in[6];
    const float* resetb = (const float*)d_in[7];
    const float* updateW= (const float*)d_in[8];
    const float* updateb= (const float*)d_in[9];
    const float* transW = (const float*)d_in[10];
    const float* transb = (const float*)d_in[11];
    const float* attW1  = (const float*)d_in[12];
    const float* attb1  = (const float*)d_in[13];
    const float* attW2  = (const float*)d_in[14];
    const float* attb2  = (const float*)d_in[15];
    const float* outW   = (const float*)d_in[16];
    const float* outb   = (const float*)d_in[17];

    char* w = (char*)d_ws;
    u16*   ws_a_bf    = (u16*)(w);                    //  4,194,304 B
    float* ws_prop    = (float*)(w + 4194304);        //  8,388,608 B
    u16*   ws_prop_bf = (u16*)(w + 12582912);         //  4,194,304 B
    float* ws_rowsum  = (float*)(w + 16777216);       //     65,536 B
    float* ws_atten   = (float*)(w + 16842752);       //     65,536 B
    float* ws_resid   = (float*)(w + 16908288);       //     16,384 B
    float* ws_W2      = (float*)(w + 16924672);       //     65,536 B
    float* ws_ebias   = (float*)(w + 16990208);       //        512 B
    u16*   ws_linkImg = (u16*)(w + 16990720);         //     32,768 B
    u16*   ws_W3Img   = (u16*)(w + 17023488);         //     32,768 B
    u16*   ws_WrImg   = (u16*)(w + 17056256);         //     65,536 B
    u16*   ws_WzImg   = (u16*)(w + 17121792);         //     65,536 B
    u16*   ws_WhImg   = (u16*)(w + 17187328);         //     65,536 B
    u16*   ws_attW1Img= (u16*)(w + 17252864);         //     32,768 B
    u16*   ws_outWImg = (u16*)(w + 17285632);         //     32,768 B  (total ~16.5 MB)

    float* out_res  = (float*)d_out;
    float* out_mul  = out_res + 4096;
    float* out_edge = out_res + 8192;
    // Scratch inside d_out edge region (dead until k_eout, which runs last):
    u16*   Eswz     = (u16*)out_edge;                 // 16.78 MB
    float* outPool  = out_edge + 4194304;             // next 8.39 MB

    hipMemsetAsync(ws_resid, 0, 32 * 128 * sizeof(float), stream);
    k_prep1<<<26, 256, 0, stream>>>(linkW, resetW, updateW, transW, attW1, outW,
                                    ws_W2, ws_linkImg, ws_WrImg, ws_WzImg, ws_WhImg,
                                    ws_attW1Img, ws_outWImg);
    k_prep2<<<9, 256, 0, stream>>>(linkW, linkb, ws_W2, ws_W3Img, ws_ebias);
    k_te<<<dim3(64, 32), 256, 0, stream>>>(edge0, Eswz, ws_resid);
    k_g0<<<dim3(8, 32), 256, 0, stream>>>(Amat, Eswz, ws_a_bf, ws_rowsum);
    k_gates<<<256, 256, 0, stream>>>(ws_a_bf, prop0, ws_prop, ws_prop_bf, ws_prop_bf, 1,
                                     ws_rowsum, ws_linkImg, ws_WrImg, ws_WzImg, ws_WhImg,
                                     linkb, resetb, updateb, transb);
    k_gates<<<256, 256, 0, stream>>>(ws_a_bf, ws_prop, ws_prop, ws_prop_bf, ws_prop_bf, 0,
                                     ws_rowsum, ws_linkImg, ws_WrImg, ws_WzImg, ws_WhImg,
                                     linkb, resetb, updateb, transb);
    k_gates<<<256, 256, 0, stream>>>(ws_a_bf, ws_prop, ws_prop, ws_prop_bf, ws_prop_bf, 0,
                                     ws_rowsum, ws_linkImg, ws_WrImg, ws_WzImg, ws_WhImg,
                                     linkb, resetb, updateb, transb);
    k_att<<<256, 256, 0, stream>>>(ws_prop_bf, ws_attW1Img, ws_outWImg, attb1, attW2, attb2,
                                   outb, ws_atten, outPool);
    k_fin<<<32, 256, 0, stream>>>(ws_atten, outPool, prop0, ws_resid, out_res, out_mul);
    k_eout<<<dim3(32, 32), 256, 0, stream>>>(edge0, ws_W3Img, ws_ebias, out_edge);
}

// Round 2
// 396.291 us; speedup vs baseline: 1.1839x; 1.1839x over previous
//
#include <hip/hip_runtime.h>
#include <hip/hip_bf16.h>

// SpatialRelation on MI355X — round 2.
// A@(E·W^t) = (A@E)·W^t => big einsum once; edges as single E0@W^3 GEMM.
// R2 change: latency-bound fix. Single-wave MFMA tiles with fragments loaded
// DIRECTLY from global (A/P row-major is fragment-contiguous; weight images
// are fragment-contiguous in L2). k_g0: K-split across the block's 4 waves
// with in-LDS reduction; register double-buffer; XCD-locality swizzle.

typedef unsigned short u16;
typedef __attribute__((ext_vector_type(4))) float f32x4;
typedef __attribute__((ext_vector_type(8))) short bf16x8;

#define DI static __device__ __forceinline__

DI u16 f2bf(float f) {
    unsigned u = __builtin_bit_cast(unsigned, f);
    return (u16)((u + 0x7fffu + ((u >> 16) & 1u)) >> 16);  // RNE
}
DI float bf2f(u16 h) { return __builtin_bit_cast(float, ((unsigned)h) << 16); }

DI bf16x8 cvt8(float4 a, float4 b) {
    u16 tmp[8] = {f2bf(a.x), f2bf(a.y), f2bf(a.z), f2bf(a.w),
                  f2bf(b.x), f2bf(b.y), f2bf(b.z), f2bf(b.w)};
    return *(const bf16x8*)tmp;
}

// B-operand image: element (k,n) at ((k>>5)*128+n)*4 + (((k>>3)&3)^((n>>1)&3)))*8 + (k&7)
DI int imgIdx(int k, int n) {
    return (((k >> 5) * 128 + n) * 4 + (((k >> 3) & 3) ^ ((n >> 1) & 3))) * 8 + (k & 7);
}
// B fragment (16B) direct from a weight/edge image in global memory.
DI bf16x8 wfragG(const u16* __restrict__ img, int kc, int tt, int l15, int quad) {
    return *(const bf16x8*)&img[(((kc * 128 + tt * 16 + l15) * 4) + (quad ^ ((l15 >> 1) & 3))) * 8];
}

#define MFMA16(a, b, c) __builtin_amdgcn_mfma_f32_16x16x32_bf16(a, b, c, 0, 0, 0)

// ---------------------------------------------------------------- prep 1
// blocks 0-63: W2 = linkW@linkW (1 output/thread). blocks 64-81: bf16 images.
__global__ __launch_bounds__(256) void k_prep1(
    const float* __restrict__ linkW, const float* __restrict__ resetW,
    const float* __restrict__ updateW, const float* __restrict__ transW,
    const float* __restrict__ attW1, const float* __restrict__ outW,
    float* __restrict__ W2, u16* __restrict__ linkImg, u16* __restrict__ WrImg,
    u16* __restrict__ WzImg, u16* __restrict__ WhImg, u16* __restrict__ attW1Img,
    u16* __restrict__ outWImg)
{
    int blk = blockIdx.x, t = threadIdx.x;
    if (blk < 64) {
        int idx = blk * 256 + t;
        int r = idx >> 7, c = idx & 127;
        float acc = 0.f;
        for (int k = 0; k < 128; k++) acc += linkW[r * 128 + k] * linkW[k * 128 + c];
        W2[r * 128 + c] = acc;
    } else {
        const float* src; u16* dst; int base;
        if (blk < 68)      { src = resetW;  dst = WrImg;    base = 64; }
        else if (blk < 72) { src = updateW; dst = WzImg;    base = 68; }
        else if (blk < 76) { src = transW;  dst = WhImg;    base = 72; }
        else if (blk < 78) { src = linkW;   dst = linkImg;  base = 76; }
        else if (blk < 80) { src = attW1;   dst = attW1Img; base = 78; }
        else               { src = outW;    dst = outWImg;  base = 80; }
        int off = (blk - base) * 8192;
        for (int i = 0; i < 32; i++) {
            int e = off + t + i * 256;
            int k = e >> 7, n = e & 127;
            dst[imgIdx(k, n)] = f2bf(src[e]);
        }
    }
}

// ---------------------------------------------------------------- prep 2
// blocks 0-63: W3 = W2@linkW -> bf16 image. block 64: ebias = b(W2+W+I).
__global__ __launch_bounds__(256) void k_prep2(
    const float* __restrict__ linkW, const float* __restrict__ linkb,
    const float* __restrict__ W2, u16* __restrict__ W3Img, float* __restrict__ ebias)
{
    int blk = blockIdx.x, t = threadIdx.x;
    if (blk < 64) {
        int idx = blk * 256 + t;
        int r = idx >> 7, c = idx & 127;
        float acc = 0.f;
        for (int k = 0; k < 128; k++) acc += W2[r * 128 + k] * linkW[k * 128 + c];
        W3Img[imgIdx(r, c)] = f2bf(acc);
    } else if (t < 128) {
        float acc = linkb[t];
        for (int k = 0; k < 128; k++) acc += linkb[k] * (W2[k * 128 + t] + linkW[k * 128 + t]);
        ebias[t] = acc;
    }
}

// ---------------------------------------------------------------- E transpose
__global__ __launch_bounds__(256) void k_te(
    const float* __restrict__ E0, u16* __restrict__ Eswz, float* __restrict__ resid)
{
    __shared__ alignas(16) u16 sT[4096];
    __shared__ float sCol[128];
    int t = threadIdx.x, kc = blockIdx.x, b = blockIdx.y;
    const float* Eb = E0 + (size_t)b * 262144 + (size_t)kc * 32 * 128;
    if (t < 128) sCol[t] = 0.f;
    float part[4] = {0.f, 0.f, 0.f, 0.f};
    int ncol = (t & 31) * 4;
    for (int i = 0; i < 4; i++) {
        int f4i = t + i * 256;
        int k5 = f4i >> 5;
        float4 v = *(const float4*)&Eb[k5 * 128 + ncol];
        int g = k5 >> 3, o = k5 & 7;
        float vv[4] = {v.x, v.y, v.z, v.w};
#pragma unroll
        for (int j = 0; j < 4; j++) {
            int n = ncol + j;
            sT[(n * 4 + (g ^ ((n >> 1) & 3))) * 8 + o] = f2bf(vv[j]);
            part[j] += vv[j];
        }
    }
    __syncthreads();
#pragma unroll
    for (int j = 0; j < 4; j++) atomicAdd(&sCol[ncol + j], part[j]);
    u16* dst = Eswz + (size_t)b * 262144 + (size_t)kc * 4096;
    ((uint4*)dst)[t] = ((const uint4*)sT)[t];
    ((uint4*)dst)[t + 256] = ((const uint4*)sT)[t + 256];
    __syncthreads();
    if (t < 128) atomicAdd(&resid[b * 128 + t], sCol[t]);
}

// ---------------------------------------------------------------- G0 = A @ E0  (+rowsum(A))
// 1024 blocks x 256 thr. Block = one 16-row strip; 4 waves split K (512 each).
// In-block LDS reduce. Block-index swizzle: all 32 strips of a batch land on
// one XCD (bx % 8 == b % 8) so Eswz[b] stays L2-resident.
__global__ __launch_bounds__(256, 3) void k_g0(
    const float* __restrict__ A, const u16* __restrict__ Eswz,
    u16* __restrict__ aOut, float* __restrict__ rowsum)
{
    __shared__ float sAcc[4][16][128];
    __shared__ float sRs[4][16];
    int t = threadIdx.x, wid = t >> 6, lane = t & 63, l15 = lane & 15, quad = lane >> 4;
    int bx = blockIdx.x;
    int g = bx >> 8, rmod = bx & 255;
    int b = (rmod & 7) + 8 * g;          // batch
    int s = (rmod >> 3) & 31;            // strip in batch
    size_t r0 = (size_t)b * 512 + (size_t)s * 16;
    const u16* Eb = Eswz + (size_t)b * 262144;
    const float* Ar = A + (r0 + l15) * 2048;
    int kbase = wid * 16;                // this wave's K-quarter (16 chunks of 32)

    f32x4 acc[8];
#pragma unroll
    for (int i = 0; i < 8; i++) acc[i] = (f32x4){0.f, 0.f, 0.f, 0.f};
    float rsum = 0.f;

    float4 xc = *(const float4*)&Ar[kbase * 32 + quad * 8];
    float4 yc = *(const float4*)&Ar[kbase * 32 + quad * 8 + 4];
    bf16x8 bc[8];
#pragma unroll
    for (int tt = 0; tt < 8; tt++) bc[tt] = wfragG(Eb, kbase, tt, l15, quad);

    for (int kc = 0; kc < 16; kc++) {
        int kg = kbase + kc;
        float4 xn, yn; bf16x8 bn[8];
        if (kc < 15) {
            xn = *(const float4*)&Ar[(kg + 1) * 32 + quad * 8];
            yn = *(const float4*)&Ar[(kg + 1) * 32 + quad * 8 + 4];
#pragma unroll
            for (int tt = 0; tt < 8; tt++) bn[tt] = wfragG(Eb, kg + 1, tt, l15, quad);
        }
        rsum += xc.x + xc.y + xc.z + xc.w + yc.x + yc.y + yc.z + yc.w;
        bf16x8 af = cvt8(xc, yc);
#pragma unroll
        for (int tt = 0; tt < 8; tt++) acc[tt] = MFMA16(af, bc[tt], acc[tt]);
        if (kc < 15) {
            xc = xn; yc = yn;
#pragma unroll
            for (int tt = 0; tt < 8; tt++) bc[tt] = bn[tt];
        }
    }
    rsum += __shfl_xor(rsum, 16);
    rsum += __shfl_xor(rsum, 32);
    if (quad == 0) sRs[wid][l15] = rsum;
#pragma unroll
    for (int tt = 0; tt < 8; tt++)
#pragma unroll
        for (int r = 0; r < 4; r++)
            sAcc[wid][quad * 4 + r][tt * 16 + l15] = acc[tt][r];
    __syncthreads();
    {
        int row = t >> 4, c8 = (t & 15) * 8;
        u16 o[8];
#pragma unroll
        for (int j = 0; j < 8; j++) {
            float v = sAcc[0][row][c8 + j] + sAcc[1][row][c8 + j] +
                      sAcc[2][row][c8 + j] + sAcc[3][row][c8 + j];
            o[j] = f2bf(v);
        }
        *(uint4*)&aOut[(r0 + row) * 128 + c8] = *(const uint4*)o;
    }
    if (t < 16)
        rowsum[r0 + t] = sRs[0][t] + sRs[1][t] + sRs[2][t] + sRs[3][t];
}

// ---------------------------------------------------------------- per-step fused GRU
// One wave per block, 16 rows. All fragments direct from global; LDS only for
// the two C-layout -> A-layout transposes (a_new, r*p).
__global__ __launch_bounds__(64) void k_gates(
    u16* __restrict__ aBuf, const float* __restrict__ pIn, float* __restrict__ pOut,
    const float* __restrict__ rowsum,
    const u16* __restrict__ linkImg, const u16* __restrict__ WrImg,
    const u16* __restrict__ WzImg, const u16* __restrict__ WhImg,
    const float* __restrict__ link_b, const float* __restrict__ reset_b,
    const float* __restrict__ update_b, const float* __restrict__ trans_b)
{
    __shared__ alignas(16) u16 sT[16 * 136];
    int t = threadIdx.x, l15 = t & 15, quad = t >> 4;
    size_t r0 = (size_t)blockIdx.x * 16;

    bf16x8 aF[4], pF[4];
#pragma unroll
    for (int kc = 0; kc < 4; kc++) {
        aF[kc] = *(const bf16x8*)&aBuf[(r0 + l15) * 128 + kc * 32 + quad * 8];
        float4 x = *(const float4*)&pIn[(r0 + l15) * 128 + kc * 32 + quad * 8];
        float4 y = *(const float4*)&pIn[(r0 + l15) * 128 + kc * 32 + quad * 8 + 4];
        pF[kc] = cvt8(x, y);
    }

    f32x4 zero4 = {0.f, 0.f, 0.f, 0.f};
    // ---- a_new = a_prev @ linkW + rowsum*link_b
    f32x4 acc[8];
#pragma unroll
    for (int i = 0; i < 8; i++) acc[i] = zero4;
#pragma unroll
    for (int kc = 0; kc < 4; kc++)
#pragma unroll
        for (int tt = 0; tt < 8; tt++)
            acc[tt] = MFMA16(aF[kc], wfragG(linkImg, kc, tt, l15, quad), acc[tt]);
    float sv[4];
#pragma unroll
    for (int r = 0; r < 4; r++) sv[r] = rowsum[r0 + quad * 4 + r];
#pragma unroll
    for (int tt = 0; tt < 8; tt++) {
        int col = tt * 16 + l15; float lb = link_b[col];
#pragma unroll
        for (int r = 0; r < 4; r++)
            sT[(quad * 4 + r) * 136 + col] = f2bf(acc[tt][r] + sv[r] * lb);
    }
    __syncthreads();
#pragma unroll
    for (int kc = 0; kc < 4; kc++)
        aF[kc] = *(const bf16x8*)&sT[l15 * 136 + kc * 32 + quad * 8];
    // store a_new to global (for next step), coalesced from LDS
#pragma unroll
    for (int i = 0; i < 4; i++) {
        int idx = t + i * 64; int row = idx >> 4, col = (idx & 15) * 8;
        *(uint4*)&aBuf[(r0 + row) * 128 + col] = *(const uint4*)&sT[row * 136 + col];
    }

    // ---- r, z = sigmoid([a_new, p] @ W)
    f32x4 aR[8], aZ[8];
#pragma unroll
    for (int i = 0; i < 8; i++) { aR[i] = zero4; aZ[i] = zero4; }
#pragma unroll
    for (int kc = 0; kc < 8; kc++) {
        bf16x8 af = (kc < 4) ? aF[kc] : pF[kc - 4];
#pragma unroll
        for (int tt = 0; tt < 8; tt++) {
            aR[tt] = MFMA16(af, wfragG(WrImg, kc, tt, l15, quad), aR[tt]);
            aZ[tt] = MFMA16(af, wfragG(WzImg, kc, tt, l15, quad), aZ[tt]);
        }
    }
    __syncthreads();   // sT (a_new frag source) fully consumed
#pragma unroll
    for (int tt = 0; tt < 8; tt++) {
        int col = tt * 16 + l15; float rb = reset_b[col], ub = update_b[col];
#pragma unroll
        for (int r = 0; r < 4; r++) {
            float rv = 1.f / (1.f + __expf(-(aR[tt][r] + rb)));
            aZ[tt][r] = 1.f / (1.f + __expf(-(aZ[tt][r] + ub)));
            float p = pIn[(r0 + quad * 4 + r) * 128 + col];
            sT[(quad * 4 + r) * 136 + col] = f2bf(rv * p);
        }
    }
    __syncthreads();
    bf16x8 rpF[4];
#pragma unroll
    for (int kc = 0; kc < 4; kc++)
        rpF[kc] = *(const bf16x8*)&sT[l15 * 136 + kc * 32 + quad * 8];

    // ---- h = tanh([a_new, r*p] @ Wh)
#pragma unroll
    for (int i = 0; i < 8; i++) aR[i] = zero4;
#pragma unroll
    for (int kc = 0; kc < 8; kc++) {
        bf16x8 af = (kc < 4) ? aF[kc] : rpF[kc - 4];
#pragma unroll
        for (int tt = 0; tt < 8; tt++)
            aR[tt] = MFMA16(af, wfragG(WhImg, kc, tt, l15, quad), aR[tt]);
    }
    // ---- GRU update (fp32)
#pragma unroll
    for (int tt = 0; tt < 8; tt++) {
        int col = tt * 16 + l15; float tb = trans_b[col];
#pragma unroll
        for (int r = 0; r < 4; r++) {
            size_t row = r0 + quad * 4 + r;
            float h = tanhf(aR[tt][r] + tb);
            float z = aZ[tt][r];
            float p = pIn[row * 128 + col];
            pOut[row * 128 + col] = (1.f - z) * p + z * h;
        }
    }
}

// ---------------------------------------------------------------- attention + out
__global__ __launch_bounds__(64) void k_att(
    const float* __restrict__ pIn, const u16* __restrict__ attW1Img,
    const u16* __restrict__ outWImg, const float* __restrict__ att_b1,
    const float* __restrict__ att_W2, const float* __restrict__ att_b2,
    const float* __restrict__ out_b, float* __restrict__ atten, float* __restrict__ outPool)
{
    int t = threadIdx.x, l15 = t & 15, quad = t >> 4;
    size_t r0 = (size_t)blockIdx.x * 16;
    bf16x8 pF[4];
#pragma unroll
    for (int kc = 0; kc < 4; kc++) {
        float4 x = *(const float4*)&pIn[(r0 + l15) * 128 + kc * 32 + quad * 8];
        float4 y = *(const float4*)&pIn[(r0 + l15) * 128 + kc * 32 + quad * 8 + 4];
        pF[kc] = cvt8(x, y);
    }
    f32x4 zero4 = {0.f, 0.f, 0.f, 0.f};
    f32x4 aA[8], aO[8];
#pragma unroll
    for (int i = 0; i < 8; i++) { aA[i] = zero4; aO[i] = zero4; }
#pragma unroll
    for (int kc = 0; kc < 4; kc++)
#pragma unroll
        for (int tt = 0; tt < 8; tt++) {
            aA[tt] = MFMA16(pF[kc], wfragG(attW1Img, kc, tt, l15, quad), aA[tt]);
            aO[tt] = MFMA16(pF[kc], wfragG(outWImg, kc, tt, l15, quad), aO[tt]);
        }
    float part[4] = {0.f, 0.f, 0.f, 0.f};
#pragma unroll
    for (int tt = 0; tt < 8; tt++) {
        int col = tt * 16 + l15;
        float b1 = att_b1[col], w2 = att_W2[col], ob = out_b[col];
#pragma unroll
        for (int r = 0; r < 4; r++) {
            part[r] += tanhf(aA[tt][r] + b1) * w2;
            outPool[(r0 + quad * 4 + r) * 128 + col] = tanhf(aO[tt][r] + ob);
        }
    }
    float b2 = att_b2[0];
#pragma unroll
    for (int r = 0; r < 4; r++) {
        float loc = part[r];
        loc += __shfl_xor(loc, 1); loc += __shfl_xor(loc, 2);
        loc += __shfl_xor(loc, 4); loc += __shfl_xor(loc, 8);
        if (l15 == 0) atten[r0 + quad * 4 + r] = loc + b2;
    }
}

// ---------------------------------------------------------------- edges out: E0@W3 + ebias
__global__ __launch_bounds__(64) void k_eout(
    const float* __restrict__ E0, const u16* __restrict__ W3Img,
    const float* __restrict__ ebias, float* __restrict__ Eout)
{
    int t = threadIdx.x, l15 = t & 15, quad = t >> 4;
    size_t r0 = (size_t)blockIdx.x * 16;   // 65536 edge-rows total
    bf16x8 eF[4];
#pragma unroll
    for (int kc = 0; kc < 4; kc++) {
        float4 x = *(const float4*)&E0[(r0 + l15) * 128 + kc * 32 + quad * 8];
        float4 y = *(const float4*)&E0[(r0 + l15) * 128 + kc * 32 + quad * 8 + 4];
        eF[kc] = cvt8(x, y);
    }
    f32x4 zero4 = {0.f, 0.f, 0.f, 0.f};
    f32x4 acc[8];
#pragma unroll
    for (int i = 0; i < 8; i++) acc[i] = zero4;
#pragma unroll
    for (int kc = 0; kc < 4; kc++)
#pragma unroll
        for (int tt = 0; tt < 8; tt++)
            acc[tt] = MFMA16(eF[kc], wfragG(W3Img, kc, tt, l15, quad), acc[tt]);
#pragma unroll
    for (int tt = 0; tt < 8; tt++) {
        int col = tt * 16 + l15; float eb = ebias[col];
#pragma unroll
        for (int r = 0; r < 4; r++)
            Eout[(r0 + quad * 4 + r) * 128 + col] = acc[tt][r] + eb;
    }
}

// ---------------------------------------------------------------- softmax-pool + residual
__global__ __launch_bounds__(256) void k_fin(
    const float* __restrict__ atten, const float* __restrict__ outPool,
    const float* __restrict__ prop0, const float* __restrict__ resid,
    float* __restrict__ outRes, float* __restrict__ outMul)
{
    __shared__ float swv[512];
    __shared__ float sred[256];
    int t = threadIdx.x, b = blockIdx.x;
    float a0 = atten[b * 512 + t], a1 = atten[b * 512 + 256 + t];
    sred[t] = fmaxf(a0, a1); __syncthreads();
    for (int s = 128; s > 0; s >>= 1) { if (t < s) sred[t] = fmaxf(sred[t], sred[t + s]); __syncthreads(); }
    float mx = sred[0]; __syncthreads();
    float e0 = __expf(a0 - mx), e1 = __expf(a1 - mx);
    swv[t] = e0; swv[t + 256] = e1;
    sred[t] = e0 + e1; __syncthreads();
    for (int s = 128; s > 0; s >>= 1) { if (t < s) sred[t] += sred[t + s]; __syncthreads(); }
    float Z = sred[0]; __syncthreads();
    int col = t & 127, half = t >> 7;
    const float* op = outPool + ((size_t)b * 512 + half * 256) * 128 + col;
    const float* pp = prop0 + ((size_t)b * 512 + half * 256) * 128 + col;
    float accM = 0.f, accN = 0.f;
    for (int n = 0; n < 256; n++) {
        accM += swv[half * 256 + n] * op[(size_t)n * 128];
        accN += pp[(size_t)n * 128];
    }
    sred[t] = accM; __syncthreads();
    float mulv = 0.f;
    if (t < 128) mulv = (sred[t] + sred[t + 128]) / Z;
    __syncthreads();
    sred[t] = accN; __syncthreads();
    if (t < 128) {
        float nodesum = sred[t] + sred[t + 128];
        float rv = (nodesum + resid[b * 128 + t]) * (1.f / 2560.f);
        outMul[b * 128 + t] = mulv;
        outRes[b * 128 + t] = fmaxf(0.f, tanhf(mulv) + rv);
    }
}

// ================================================================ launch
extern "C" void kernel_launch(void* const* d_in, const int* in_sizes, int n_in,
                              void* d_out, int out_size, void* d_ws, size_t ws_size,
                              hipStream_t stream)
{
    const float* prop0  = (const float*)d_in[0];
    const float* edge0  = (const float*)d_in[1];
    const float* Amat   = (const float*)d_in[2];
    const float* linkW  = (const float*)d_in[4];
    const float* linkb  = (const float*)d_in[5];
    const float* resetW = (const float*)d_in[6];
    const float* resetb = (const float*)d_in[7];
    const float* updateW= (const float*)d_in[8];
    const float* updateb= (const float*)d_in[9];
    const float* transW = (const float*)d_in[10];
    const float* transb = (const float*)d_in[11];
    const float* attW1  = (const float*)d_in[12];
    const float* attb1  = (const float*)d_in[13];
    const float* attW2  = (const float*)d_in[14];
    const float* attb2  = (const float*)d_in[15];
    const float* outW   = (const float*)d_in[16];
    const float* outb   = (const float*)d_in[17];

    char* w = (char*)d_ws;
    u16*   ws_a_bf    = (u16*)(w);                    //  4,194,304 B
    float* ws_prop    = (float*)(w + 4194304);        //  8,388,608 B
    float* ws_rowsum  = (float*)(w + 12582912);       //     65,536 B
    float* ws_atten   = (float*)(w + 12648448);       //     65,536 B
    float* ws_resid   = (float*)(w + 12713984);       //     16,384 B
    float* ws_W2      = (float*)(w + 12730368);       //     65,536 B
    float* ws_ebias   = (float*)(w + 12795904);       //        512 B
    u16*   ws_linkImg = (u16*)(w + 12796416);         //     32,768 B
    u16*   ws_W3Img   = (u16*)(w + 12829184);         //     32,768 B
    u16*   ws_WrImg   = (u16*)(w + 12861952);         //     65,536 B
    u16*   ws_WzImg   = (u16*)(w + 12927488);         //     65,536 B
    u16*   ws_WhImg   = (u16*)(w + 12993024);         //     65,536 B
    u16*   ws_attW1Img= (u16*)(w + 13058560);         //     32,768 B
    u16*   ws_outWImg = (u16*)(w + 13091328);         //     32,768 B  (~13.1 MB)

    float* out_res  = (float*)d_out;
    float* out_mul  = out_res + 4096;
    float* out_edge = out_res + 8192;
    // Scratch inside d_out edge region (dead until k_eout, which runs last):
    u16*   Eswz     = (u16*)out_edge;                 // 16.78 MB
    float* outPool  = out_edge + 4194304;             // next 8.39 MB

    hipMemsetAsync(ws_resid, 0, 32 * 128 * sizeof(float), stream);
    k_prep1<<<82, 256, 0, stream>>>(linkW, resetW, updateW, transW, attW1, outW,
                                    ws_W2, ws_linkImg, ws_WrImg, ws_WzImg, ws_WhImg,
                                    ws_attW1Img, ws_outWImg);
    k_prep2<<<65, 256, 0, stream>>>(linkW, linkb, ws_W2, ws_W3Img, ws_ebias);
    k_te<<<dim3(64, 32), 256, 0, stream>>>(edge0, Eswz, ws_resid);
    k_g0<<<1024, 256, 0, stream>>>(Amat, Eswz, ws_a_bf, ws_rowsum);
    k_gates<<<1024, 64, 0, stream>>>(ws_a_bf, prop0, ws_prop, ws_rowsum,
                                     ws_linkImg, ws_WrImg, ws_WzImg, ws_WhImg,
                                     linkb, resetb, updateb, transb);
    k_gates<<<1024, 64, 0, stream>>>(ws_a_bf, ws_prop, ws_prop, ws_rowsum,
                                     ws_linkImg, ws_WrImg, ws_WzImg, ws_WhImg,
                                     linkb, resetb, updateb, transb);
    k_gates<<<1024, 64, 0, stream>>>(ws_a_bf, ws_prop, ws_prop, ws_rowsum,
                                     ws_linkImg, ws_WrImg, ws_WzImg, ws_WhImg,
                                     linkb, resetb, updateb, transb);
    k_att<<<1024, 64, 0, stream>>>(ws_prop, ws_attW1Img, ws_outWImg, attb1, attW2, attb2,
                                   outb, ws_atten, outPool);
    k_fin<<<32, 256, 0, stream>>>(ws_atten, outPool, prop0, ws_resid, out_res, out_mul);
    k_eout<<<4096, 64, 0, stream>>>(edge0, ws_W3Img, ws_ebias, out_edge);
}

// Round 3
// 394.170 us; speedup vs baseline: 1.1903x; 1.0054x over previous
//
#include <hip/hip_runtime.h>
#include <hip/hip_bf16.h>

// SpatialRelation on MI355X — round 3.
// A@(E·W^t) = (A@E)·W^t => big einsum once; edges as single E0@W^3 GEMM.
// R3: hand-pipelined weight-fragment prefetch (k_g0-style wc/wn double
// buffering) in all MFMA kernels — R2 showed the compiler serializes
// load->mfma at 1 wave/SIMD without it. k_att fused into gates step 3.
// Preps K-split. One-wave blocks drop __syncthreads (wave-private LDS).

typedef unsigned short u16;
typedef __attribute__((ext_vector_type(4))) float f32x4;
typedef __attribute__((ext_vector_type(8))) short bf16x8;

#define DI static __device__ __forceinline__

DI u16 f2bf(float f) {
    unsigned u = __builtin_bit_cast(unsigned, f);
    return (u16)((u + 0x7fffu + ((u >> 16) & 1u)) >> 16);  // RNE
}
DI float bf2f(u16 h) { return __builtin_bit_cast(float, ((unsigned)h) << 16); }

DI bf16x8 cvt8(float4 a, float4 b) {
    u16 tmp[8] = {f2bf(a.x), f2bf(a.y), f2bf(a.z), f2bf(a.w),
                  f2bf(b.x), f2bf(b.y), f2bf(b.z), f2bf(b.w)};
    return *(const bf16x8*)tmp;
}

// B-operand image: element (k,n) at (((k>>5)*128+n)*4 + (((k>>3)&3)^((n>>1)&3)))*8 + (k&7)
DI int imgIdx(int k, int n) {
    return (((k >> 5) * 128 + n) * 4 + (((k >> 3) & 3) ^ ((n >> 1) & 3))) * 8 + (k & 7);
}
// B fragment (16B) direct from a weight/edge image in global memory.
DI bf16x8 wfragG(const u16* __restrict__ img, int kc, int tt, int l15, int quad) {
    return *(const bf16x8*)&img[(((kc * 128 + tt * 16 + l15) * 4) + (quad ^ ((l15 >> 1) & 3))) * 8];
}

#define MFMA16(a, b, c) __builtin_amdgcn_mfma_f32_16x16x32_bf16(a, b, c, 0, 0, 0)

// ---------------------------------------------------------------- prep 1
// blocks 0-255: W2 = linkW@linkW, K-split x4 + shfl reduce. 256+: bf16 images.
__global__ __launch_bounds__(256) void k_prep1(
    const float* __restrict__ linkW, const float* __restrict__ resetW,
    const float* __restrict__ updateW, const float* __restrict__ transW,
    const float* __restrict__ attW1, const float* __restrict__ outW,
    float* __restrict__ W2, u16* __restrict__ linkImg, u16* __restrict__ WrImg,
    u16* __restrict__ WzImg, u16* __restrict__ WhImg, u16* __restrict__ attW1Img,
    u16* __restrict__ outWImg)
{
    int blk = blockIdx.x, t = threadIdx.x;
    if (blk < 256) {
        int idx = blk * 256 + t;          // [0, 65536)
        int out = idx >> 2, q = idx & 3;
        int r = out >> 7, c = out & 127;
        const float* ar = linkW + r * 128 + q * 32;
        float acc = 0.f;
#pragma unroll
        for (int k = 0; k < 32; k++) acc += ar[k] * linkW[(q * 32 + k) * 128 + c];
        acc += __shfl_xor(acc, 1);
        acc += __shfl_xor(acc, 2);
        if (q == 0) W2[out] = acc;
    } else {
        const float* src; u16* dst; int base;
        if (blk < 260)      { src = resetW;  dst = WrImg;    base = 256; }
        else if (blk < 264) { src = updateW; dst = WzImg;    base = 260; }
        else if (blk < 268) { src = transW;  dst = WhImg;    base = 264; }
        else if (blk < 270) { src = linkW;   dst = linkImg;  base = 268; }
        else if (blk < 272) { src = attW1;   dst = attW1Img; base = 270; }
        else                { src = outW;    dst = outWImg;  base = 272; }
        int off = (blk - base) * 8192;
        for (int i = 0; i < 32; i++) {
            int e = off + t + i * 256;
            int k = e >> 7, n = e & 127;
            dst[imgIdx(k, n)] = f2bf(src[e]);
        }
    }
}

// ---------------------------------------------------------------- prep 2
// blocks 0-255: W3 = W2@linkW (K-split x4) -> bf16 image. block 256: ebias.
__global__ __launch_bounds__(256) void k_prep2(
    const float* __restrict__ linkW, const float* __restrict__ linkb,
    const float* __restrict__ W2, u16* __restrict__ W3Img, float* __restrict__ ebias)
{
    int blk = blockIdx.x, t = threadIdx.x;
    if (blk < 256) {
        int idx = blk * 256 + t;
        int out = idx >> 2, q = idx & 3;
        int r = out >> 7, c = out & 127;
        const float* ar = W2 + r * 128 + q * 32;
        float acc = 0.f;
#pragma unroll
        for (int k = 0; k < 32; k++) acc += ar[k] * linkW[(q * 32 + k) * 128 + c];
        acc += __shfl_xor(acc, 1);
        acc += __shfl_xor(acc, 2);
        if (q == 0) W3Img[imgIdx(r, c)] = f2bf(acc);
    } else if (t < 128) {
        float acc = linkb[t];
#pragma unroll 8
        for (int k = 0; k < 128; k++) acc += linkb[k] * (W2[k * 128 + t] + linkW[k * 128 + t]);
        ebias[t] = acc;
    }
}

// ---------------------------------------------------------------- E transpose
__global__ __launch_bounds__(256) void k_te(
    const float* __restrict__ E0, u16* __restrict__ Eswz, float* __restrict__ resid)
{
    __shared__ alignas(16) u16 sT[4096];
    __shared__ float sCol[128];
    int t = threadIdx.x, kc = blockIdx.x, b = blockIdx.y;
    const float* Eb = E0 + (size_t)b * 262144 + (size_t)kc * 32 * 128;
    if (t < 128) sCol[t] = 0.f;
    float part[4] = {0.f, 0.f, 0.f, 0.f};
    int ncol = (t & 31) * 4;
    for (int i = 0; i < 4; i++) {
        int f4i = t + i * 256;
        int k5 = f4i >> 5;
        float4 v = *(const float4*)&Eb[k5 * 128 + ncol];
        int g = k5 >> 3, o = k5 & 7;
        float vv[4] = {v.x, v.y, v.z, v.w};
#pragma unroll
        for (int j = 0; j < 4; j++) {
            int n = ncol + j;
            sT[(n * 4 + (g ^ ((n >> 1) & 3))) * 8 + o] = f2bf(vv[j]);
            part[j] += vv[j];
        }
    }
    __syncthreads();
#pragma unroll
    for (int j = 0; j < 4; j++) atomicAdd(&sCol[ncol + j], part[j]);
    u16* dst = Eswz + (size_t)b * 262144 + (size_t)kc * 4096;
    ((uint4*)dst)[t] = ((const uint4*)sT)[t];
    ((uint4*)dst)[t + 256] = ((const uint4*)sT)[t + 256];
    __syncthreads();
    if (t < 128) atomicAdd(&resid[b * 128 + t], sCol[t]);
}

// ---------------------------------------------------------------- G0 = A @ E0  (+rowsum(A))
__global__ __launch_bounds__(256, 3) void k_g0(
    const float* __restrict__ A, const u16* __restrict__ Eswz,
    u16* __restrict__ aOut, float* __restrict__ rowsum)
{
    __shared__ float sAcc[4][16][128];
    __shared__ float sRs[4][16];
    int t = threadIdx.x, wid = t >> 6, lane = t & 63, l15 = lane & 15, quad = lane >> 4;
    int bx = blockIdx.x;
    int g = bx >> 8, rmod = bx & 255;
    int b = (rmod & 7) + 8 * g;          // batch (XCD-local Eswz)
    int s = (rmod >> 3) & 31;            // strip in batch
    size_t r0 = (size_t)b * 512 + (size_t)s * 16;
    const u16* Eb = Eswz + (size_t)b * 262144;
    const float* Ar = A + (r0 + l15) * 2048;
    int kbase = wid * 16;                // this wave's K-quarter

    f32x4 acc[8];
#pragma unroll
    for (int i = 0; i < 8; i++) acc[i] = (f32x4){0.f, 0.f, 0.f, 0.f};
    float rsum = 0.f;

    float4 xc = *(const float4*)&Ar[kbase * 32 + quad * 8];
    float4 yc = *(const float4*)&Ar[kbase * 32 + quad * 8 + 4];
    bf16x8 bc[8];
#pragma unroll
    for (int tt = 0; tt < 8; tt++) bc[tt] = wfragG(Eb, kbase, tt, l15, quad);

    for (int kc = 0; kc < 16; kc++) {
        int kg = kbase + kc;
        float4 xn, yn; bf16x8 bn[8];
        if (kc < 15) {
            xn = *(const float4*)&Ar[(kg + 1) * 32 + quad * 8];
            yn = *(const float4*)&Ar[(kg + 1) * 32 + quad * 8 + 4];
#pragma unroll
            for (int tt = 0; tt < 8; tt++) bn[tt] = wfragG(Eb, kg + 1, tt, l15, quad);
        }
        rsum += xc.x + xc.y + xc.z + xc.w + yc.x + yc.y + yc.z + yc.w;
        bf16x8 af = cvt8(xc, yc);
#pragma unroll
        for (int tt = 0; tt < 8; tt++) acc[tt] = MFMA16(af, bc[tt], acc[tt]);
        if (kc < 15) {
            xc = xn; yc = yn;
#pragma unroll
            for (int tt = 0; tt < 8; tt++) bc[tt] = bn[tt];
        }
    }
    rsum += __shfl_xor(rsum, 16);
    rsum += __shfl_xor(rsum, 32);
    if (quad == 0) sRs[wid][l15] = rsum;
#pragma unroll
    for (int tt = 0; tt < 8; tt++)
#pragma unroll
        for (int r = 0; r < 4; r++)
            sAcc[wid][quad * 4 + r][tt * 16 + l15] = acc[tt][r];
    __syncthreads();
    {
        int row = t >> 4, c8 = (t & 15) * 8;
        u16 o[8];
#pragma unroll
        for (int j = 0; j < 8; j++) {
            float v = sAcc[0][row][c8 + j] + sAcc[1][row][c8 + j] +
                      sAcc[2][row][c8 + j] + sAcc[3][row][c8 + j];
            o[j] = f2bf(v);
        }
        *(uint4*)&aOut[(r0 + row) * 128 + c8] = *(const uint4*)o;
    }
    if (t < 16)
        rowsum[r0 + t] = sRs[0][t] + sRs[1][t] + sRs[2][t] + sRs[3][t];
}

// ---------------------------------------------------------------- per-step fused GRU
// One wave / 16 rows. Hand-pipelined weight-fragment prefetch (wc/wn).
// DO_ATT=1 (step 3): fuses attention+out GEMMs; skips p/a stores.
template<int DO_ATT>
__global__ __launch_bounds__(64) void k_gates_t(
    u16* __restrict__ aBuf, const float* __restrict__ pIn, float* __restrict__ pOut,
    u16* __restrict__ pBfOut, const u16* __restrict__ pBfIn, int first,
    const float* __restrict__ rowsum,
    const u16* __restrict__ linkImg, const u16* __restrict__ WrImg,
    const u16* __restrict__ WzImg, const u16* __restrict__ WhImg,
    const u16* __restrict__ attW1Img, const u16* __restrict__ outWImg,
    const float* __restrict__ link_b, const float* __restrict__ reset_b,
    const float* __restrict__ update_b, const float* __restrict__ trans_b,
    const float* __restrict__ att_b1, const float* __restrict__ att_W2,
    const float* __restrict__ att_b2, const float* __restrict__ out_b,
    float* __restrict__ atten, float* __restrict__ outPool)
{
    __shared__ alignas(16) u16 sT[16 * 136];   // wave-private: no barriers needed
    int t = threadIdx.x, l15 = t & 15, quad = t >> 4;
    size_t r0 = (size_t)blockIdx.x * 16;
    f32x4 zero4 = {0.f, 0.f, 0.f, 0.f};

    // A-side fragments (batched independent loads)
    bf16x8 aF[4], pF[4];
#pragma unroll
    for (int kc = 0; kc < 4; kc++)
        aF[kc] = *(const bf16x8*)&aBuf[(r0 + l15) * 128 + kc * 32 + quad * 8];
    if (first) {
#pragma unroll
        for (int kc = 0; kc < 4; kc++) {
            float4 x = *(const float4*)&pIn[(r0 + l15) * 128 + kc * 32 + quad * 8];
            float4 y = *(const float4*)&pIn[(r0 + l15) * 128 + kc * 32 + quad * 8 + 4];
            pF[kc] = cvt8(x, y);
        }
    } else {
#pragma unroll
        for (int kc = 0; kc < 4; kc++)
            pF[kc] = *(const bf16x8*)&pBfIn[(r0 + l15) * 128 + kc * 32 + quad * 8];
    }

    // ---- a_new = a_prev @ linkW + rowsum*link_b  (pipelined)
    f32x4 acc[8];
#pragma unroll
    for (int i = 0; i < 8; i++) acc[i] = zero4;
    {
        bf16x8 wc[8], wn[8];
#pragma unroll
        for (int tt = 0; tt < 8; tt++) wc[tt] = wfragG(linkImg, 0, tt, l15, quad);
#pragma unroll
        for (int kc = 0; kc < 4; kc++) {
            if (kc < 3)
#pragma unroll
                for (int tt = 0; tt < 8; tt++) wn[tt] = wfragG(linkImg, kc + 1, tt, l15, quad);
#pragma unroll
            for (int tt = 0; tt < 8; tt++) acc[tt] = MFMA16(aF[kc], wc[tt], acc[tt]);
            if (kc < 3)
#pragma unroll
                for (int tt = 0; tt < 8; tt++) wc[tt] = wn[tt];
        }
    }
    float sv[4];
#pragma unroll
    for (int r = 0; r < 4; r++) sv[r] = rowsum[r0 + quad * 4 + r];
#pragma unroll
    for (int tt = 0; tt < 8; tt++) {
        int col = tt * 16 + l15; float lb = link_b[col];
#pragma unroll
        for (int r = 0; r < 4; r++)
            sT[(quad * 4 + r) * 136 + col] = f2bf(acc[tt][r] + sv[r] * lb);
    }
    // reload a_new fragments (lgkmcnt orders ds_write->ds_read within the wave)
#pragma unroll
    for (int kc = 0; kc < 4; kc++)
        aF[kc] = *(const bf16x8*)&sT[l15 * 136 + kc * 32 + quad * 8];
    if (!DO_ATT) {
        // store a_new for the next step
#pragma unroll
        for (int i = 0; i < 4; i++) {
            int idx = t + i * 64; int row = idx >> 4, col = (idx & 15) * 8;
            *(uint4*)&aBuf[(r0 + row) * 128 + col] = *(const uint4*)&sT[row * 136 + col];
        }
    }

    // ---- r, z = sigmoid([a_new, p] @ W)  (pipelined, dual weight streams)
    f32x4 aR[8], aZ[8];
#pragma unroll
    for (int i = 0; i < 8; i++) { aR[i] = zero4; aZ[i] = zero4; }
    {
        bf16x8 rc[8], zc[8], rn[8], zn[8];
#pragma unroll
        for (int tt = 0; tt < 8; tt++) {
            rc[tt] = wfragG(WrImg, 0, tt, l15, quad);
            zc[tt] = wfragG(WzImg, 0, tt, l15, quad);
        }
#pragma unroll
        for (int kc = 0; kc < 8; kc++) {
            if (kc < 7)
#pragma unroll
                for (int tt = 0; tt < 8; tt++) {
                    rn[tt] = wfragG(WrImg, kc + 1, tt, l15, quad);
                    zn[tt] = wfragG(WzImg, kc + 1, tt, l15, quad);
                }
            bf16x8 af = (kc < 4) ? aF[kc] : pF[kc - 4];
#pragma unroll
            for (int tt = 0; tt < 8; tt++) {
                aR[tt] = MFMA16(af, rc[tt], aR[tt]);
                aZ[tt] = MFMA16(af, zc[tt], aZ[tt]);
            }
            if (kc < 7)
#pragma unroll
                for (int tt = 0; tt < 8; tt++) { rc[tt] = rn[tt]; zc[tt] = zn[tt]; }
        }
    }
    // sigmoid epilogue; rp = r*p -> sT (overwrites a_new copy; aF already in regs)
#pragma unroll
    for (int tt = 0; tt < 8; tt++) {
        int col = tt * 16 + l15; float rb = reset_b[col], ub = update_b[col];
#pragma unroll
        for (int r = 0; r < 4; r++) {
            float rv = 1.f / (1.f + __expf(-(aR[tt][r] + rb)));
            aZ[tt][r] = 1.f / (1.f + __expf(-(aZ[tt][r] + ub)));
            float p = pIn[(r0 + quad * 4 + r) * 128 + col];
            sT[(quad * 4 + r) * 136 + col] = f2bf(rv * p);
        }
    }
    bf16x8 rpF[4];
#pragma unroll
    for (int kc = 0; kc < 4; kc++)
        rpF[kc] = *(const bf16x8*)&sT[l15 * 136 + kc * 32 + quad * 8];

    // ---- h = tanh([a_new, r*p] @ Wh)  (pipelined)
#pragma unroll
    for (int i = 0; i < 8; i++) aR[i] = zero4;
    {
        bf16x8 wc[8], wn[8];
#pragma unroll
        for (int tt = 0; tt < 8; tt++) wc[tt] = wfragG(WhImg, 0, tt, l15, quad);
#pragma unroll
        for (int kc = 0; kc < 8; kc++) {
            if (kc < 7)
#pragma unroll
                for (int tt = 0; tt < 8; tt++) wn[tt] = wfragG(WhImg, kc + 1, tt, l15, quad);
            bf16x8 af = (kc < 4) ? aF[kc] : rpF[kc - 4];
#pragma unroll
            for (int tt = 0; tt < 8; tt++) aR[tt] = MFMA16(af, wc[tt], aR[tt]);
            if (kc < 7)
#pragma unroll
                for (int tt = 0; tt < 8; tt++) wc[tt] = wn[tt];
        }
    }
    // ---- GRU update: p_new = (1-z)p + z tanh(h+b)   (fp32 p path)
#pragma unroll
    for (int tt = 0; tt < 8; tt++) {
        int col = tt * 16 + l15; float tb = trans_b[col];
#pragma unroll
        for (int r = 0; r < 4; r++) {
            size_t row = r0 + quad * 4 + r;
            float h = tanhf(aR[tt][r] + tb);
            float z = aZ[tt][r];
            float p = pIn[row * 128 + col];
            float pn = (1.f - z) * p + z * h;
            acc[tt][r] = pn;                           // reuse acc as p_new (C layout)
            if (!DO_ATT) pOut[row * 128 + col] = pn;
        }
    }
    if (!DO_ATT) {
        // bf16 copy of p_new -> sT -> coalesced store (frag source for next step)
#pragma unroll
        for (int tt = 0; tt < 8; tt++) {
            int col = tt * 16 + l15;
#pragma unroll
            for (int r = 0; r < 4; r++)
                sT[(quad * 4 + r) * 136 + col] = f2bf(acc[tt][r]);
        }
#pragma unroll
        for (int i = 0; i < 4; i++) {
            int idx = t + i * 64; int row = idx >> 4, col = (idx & 15) * 8;
            *(uint4*)&pBfOut[(r0 + row) * 128 + col] = *(const uint4*)&sT[row * 136 + col];
        }
        return;
    }

    // ================= DO_ATT: fused attention + out =================
    // p_new (C layout in acc) -> sT -> A fragments
#pragma unroll
    for (int tt = 0; tt < 8; tt++) {
        int col = tt * 16 + l15;
#pragma unroll
        for (int r = 0; r < 4; r++)
            sT[(quad * 4 + r) * 136 + col] = f2bf(acc[tt][r]);
    }
    bf16x8 pnF[4];
#pragma unroll
    for (int kc = 0; kc < 4; kc++)
        pnF[kc] = *(const bf16x8*)&sT[l15 * 136 + kc * 32 + quad * 8];

    f32x4 aA[8], aO[8];
#pragma unroll
    for (int i = 0; i < 8; i++) { aA[i] = zero4; aO[i] = zero4; }
    {
        bf16x8 ac[8], oc[8], an[8], on[8];
#pragma unroll
        for (int tt = 0; tt < 8; tt++) {
            ac[tt] = wfragG(attW1Img, 0, tt, l15, quad);
            oc[tt] = wfragG(outWImg, 0, tt, l15, quad);
        }
#pragma unroll
        for (int kc = 0; kc < 4; kc++) {
            if (kc < 3)
#pragma unroll
                for (int tt = 0; tt < 8; tt++) {
                    an[tt] = wfragG(attW1Img, kc + 1, tt, l15, quad);
                    on[tt] = wfragG(outWImg, kc + 1, tt, l15, quad);
                }
#pragma unroll
            for (int tt = 0; tt < 8; tt++) {
                aA[tt] = MFMA16(pnF[kc], ac[tt], aA[tt]);
                aO[tt] = MFMA16(pnF[kc], oc[tt], aO[tt]);
            }
            if (kc < 3)
#pragma unroll
                for (int tt = 0; tt < 8; tt++) { ac[tt] = an[tt]; oc[tt] = on[tt]; }
        }
    }
    float part[4] = {0.f, 0.f, 0.f, 0.f};
#pragma unroll
    for (int tt = 0; tt < 8; tt++) {
        int col = tt * 16 + l15;
        float b1 = att_b1[col], w2 = att_W2[col], ob = out_b[col];
#pragma unroll
        for (int r = 0; r < 4; r++) {
            part[r] += tanhf(aA[tt][r] + b1) * w2;
            outPool[(r0 + quad * 4 + r) * 128 + col] = tanhf(aO[tt][r] + ob);
        }
    }
    float b2 = att_b2[0];
#pragma unroll
    for (int r = 0; r < 4; r++) {
        float loc = part[r];
        loc += __shfl_xor(loc, 1); loc += __shfl_xor(loc, 2);
        loc += __shfl_xor(loc, 4); loc += __shfl_xor(loc, 8);
        if (l15 == 0) atten[r0 + quad * 4 + r] = loc + b2;
    }
}

// ---------------------------------------------------------------- edges out: E0@W3 + ebias
__global__ __launch_bounds__(64) void k_eout(
    const float* __restrict__ E0, const u16* __restrict__ W3Img,
    const float* __restrict__ ebias, float* __restrict__ Eout)
{
    int t = threadIdx.x, l15 = t & 15, quad = t >> 4;
    size_t r0 = (size_t)blockIdx.x * 16;
    bf16x8 eF[4];
#pragma unroll
    for (int kc = 0; kc < 4; kc++) {
        float4 x = *(const float4*)&E0[(r0 + l15) * 128 + kc * 32 + quad * 8];
        float4 y = *(const float4*)&E0[(r0 + l15) * 128 + kc * 32 + quad * 8 + 4];
        eF[kc] = cvt8(x, y);
    }
    f32x4 acc[8];
#pragma unroll
    for (int i = 0; i < 8; i++) acc[i] = (f32x4){0.f, 0.f, 0.f, 0.f};
    {
        bf16x8 wc[8], wn[8];
#pragma unroll
        for (int tt = 0; tt < 8; tt++) wc[tt] = wfragG(W3Img, 0, tt, l15, quad);
#pragma unroll
        for (int kc = 0; kc < 4; kc++) {
            if (kc < 3)
#pragma unroll
                for (int tt = 0; tt < 8; tt++) wn[tt] = wfragG(W3Img, kc + 1, tt, l15, quad);
#pragma unroll
            for (int tt = 0; tt < 8; tt++) acc[tt] = MFMA16(eF[kc], wc[tt], acc[tt]);
            if (kc < 3)
#pragma unroll
                for (int tt = 0; tt < 8; tt++) wc[tt] = wn[tt];
        }
    }
#pragma unroll
    for (int tt = 0; tt < 8; tt++) {
        int col = tt * 16 + l15; float eb = ebias[col];
#pragma unroll
        for (int r = 0; r < 4; r++)
            Eout[(r0 + quad * 4 + r) * 128 + col] = acc[tt][r] + eb;
    }
}

// ---------------------------------------------------------------- softmax-pool + residual
__global__ __launch_bounds__(512) void k_fin(
    const float* __restrict__ atten, const float* __restrict__ outPool,
    const float* __restrict__ prop0, const float* __restrict__ resid,
    float* __restrict__ outRes, float* __restrict__ outMul)
{
    __shared__ float swv[512];
    __shared__ float sred[512];
    __shared__ float sacc[8][128];
    int t = threadIdx.x, b = blockIdx.x;
    float a = atten[b * 512 + t];
    sred[t] = a; __syncthreads();
    for (int s = 256; s > 0; s >>= 1) { if (t < s) sred[t] = fmaxf(sred[t], sred[t + s]); __syncthreads(); }
    float mx = sred[0]; __syncthreads();
    float e = __expf(a - mx);
    swv[t] = e; sred[t] = e; __syncthreads();
    for (int s = 256; s > 0; s >>= 1) { if (t < s) sred[t] += sred[t + s]; __syncthreads(); }
    float Z = sred[0]; __syncthreads();
    int col = t & 127, q = t >> 7;
    const float* op = outPool + ((size_t)b * 512 + q * 128) * 128 + col;
    const float* pp = prop0 + ((size_t)b * 512 + q * 128) * 128 + col;
    float accM = 0.f, accN = 0.f;
    for (int n = 0; n < 128; n++) {
        accM += swv[q * 128 + n] * op[(size_t)n * 128];
        accN += pp[(size_t)n * 128];
    }
    sacc[q][col] = accM; sacc[4 + q][col] = accN;
    __syncthreads();
    if (t < 128) {
        float mulv = (sacc[0][t] + sacc[1][t] + sacc[2][t] + sacc[3][t]) / Z;
        float nodesum = sacc[4][t] + sacc[5][t] + sacc[6][t] + sacc[7][t];
        float rv = (nodesum + resid[b * 128 + t]) * (1.f / 2560.f);
        outMul[b * 128 + t] = mulv;
        outRes[b * 128 + t] = fmaxf(0.f, tanhf(mulv) + rv);
    }
}

// ================================================================ launch
extern "C" void kernel_launch(void* const* d_in, const int* in_sizes, int n_in,
                              void* d_out, int out_size, void* d_ws, size_t ws_size,
                              hipStream_t stream)
{
    const float* prop0  = (const float*)d_in[0];
    const float* edge0  = (const float*)d_in[1];
    const float* Amat   = (const float*)d_in[2];
    const float* linkW  = (const float*)d_in[4];
    const float* linkb  = (const float*)d_in[5];
    const float* resetW = (const float*)d_in[6];
    const float* resetb = (const float*)d_in[7];
    const float* updateW= (const float*)d_in[8];
    const float* updateb= (const float*)d_in[9];
    const float* transW = (const float*)d_in[10];
    const float* transb = (const float*)d_in[11];
    const float* attW1  = (const float*)d_in[12];
    const float* attb1  = (const float*)d_in[13];
    const float* attW2  = (const float*)d_in[14];
    const float* attb2  = (const float*)d_in[15];
    const float* outW   = (const float*)d_in[16];
    const float* outb   = (const float*)d_in[17];

    char* w = (char*)d_ws;
    u16*   ws_a_bf    = (u16*)(w);                    //  4,194,304 B
    float* ws_prop    = (float*)(w + 4194304);        //  8,388,608 B
    u16*   ws_prop_bf = (u16*)(w + 12582912);         //  4,194,304 B
    float* ws_rowsum  = (float*)(w + 16777216);       //     65,536 B
    float* ws_atten   = (float*)(w + 16842752);       //     65,536 B
    float* ws_resid   = (float*)(w + 16908288);       //     16,384 B
    float* ws_W2      = (float*)(w + 16924672);       //     65,536 B
    float* ws_ebias   = (float*)(w + 16990208);       //        512 B
    u16*   ws_linkImg = (u16*)(w + 16990720);         //     32,768 B
    u16*   ws_W3Img   = (u16*)(w + 17023488);         //     32,768 B
    u16*   ws_WrImg   = (u16*)(w + 17056256);         //     65,536 B
    u16*   ws_WzImg   = (u16*)(w + 17121792);         //     65,536 B
    u16*   ws_WhImg   = (u16*)(w + 17187328);         //     65,536 B
    u16*   ws_attW1Img= (u16*)(w + 17252864);         //     32,768 B
    u16*   ws_outWImg = (u16*)(w + 17285632);         //     32,768 B  (~17.3 MB)

    float* out_res  = (float*)d_out;
    float* out_mul  = out_res + 4096;
    float* out_edge = out_res + 8192;
    // Scratch inside d_out edge region (dead until k_eout, which runs last):
    u16*   Eswz     = (u16*)out_edge;                 // 16.78 MB
    float* outPool  = out_edge + 4194304;             // next 8.39 MB

    hipMemsetAsync(ws_resid, 0, 32 * 128 * sizeof(float), stream);
    k_prep1<<<274, 256, 0, stream>>>(linkW, resetW, updateW, transW, attW1, outW,
                                     ws_W2, ws_linkImg, ws_WrImg, ws_WzImg, ws_WhImg,
                                     ws_attW1Img, ws_outWImg);
    k_prep2<<<257, 256, 0, stream>>>(linkW, linkb, ws_W2, ws_W3Img, ws_ebias);
    k_te<<<dim3(64, 32), 256, 0, stream>>>(edge0, Eswz, ws_resid);
    k_g0<<<1024, 256, 0, stream>>>(Amat, Eswz, ws_a_bf, ws_rowsum);
    k_gates_t<0><<<1024, 64, 0, stream>>>(ws_a_bf, prop0, ws_prop, ws_prop_bf, ws_prop_bf, 1,
                                          ws_rowsum, ws_linkImg, ws_WrImg, ws_WzImg, ws_WhImg,
                                          ws_attW1Img, ws_outWImg,
                                          linkb, resetb, updateb, transb,
                                          attb1, attW2, attb2, outb, ws_atten, outPool);
    k_gates_t<0><<<1024, 64, 0, stream>>>(ws_a_bf, ws_prop, ws_prop, ws_prop_bf, ws_prop_bf, 0,
                                          ws_rowsum, ws_linkImg, ws_WrImg, ws_WzImg, ws_WhImg,
                                          ws_attW1Img, ws_outWImg,
                                          linkb, resetb, updateb, transb,
                                          attb1, attW2, attb2, outb, ws_atten, outPool);
    k_gates_t<1><<<1024, 64, 0, stream>>>(ws_a_bf, ws_prop, ws_prop, ws_prop_bf, ws_prop_bf, 0,
                                          ws_rowsum, ws_linkImg, ws_WrImg, ws_WzImg, ws_WhImg,
                                          ws_attW1Img, ws_outWImg,
                                          linkb, resetb, updateb, transb,
                                          attb1, attW2, attb2, outb, ws_atten, outPool);
    k_fin<<<32, 512, 0, stream>>>(ws_atten, outPool, prop0, ws_resid, out_res, out_mul);
    k_eout<<<4096, 64, 0, stream>>>(edge0, ws_W3Img, ws_ebias, out_edge);
}

// Round 4
// 376.286 us; speedup vs baseline: 1.2469x; 1.0475x over previous
//
#include <hip/hip_runtime.h>
#include <hip/hip_bf16.h>

// SpatialRelation on MI355X — round 4.
// A@(E·W^t) = (A@E)·W^t => big einsum once; edges as single E0@W^3 GEMM.
// R4: the GRU recurrence is ROW-LOCAL => all 3 steps + attention fused into
// ONE kernel (k_steps). a/p state lives in registers+LDS across steps; zero
// intermediate global traffic. Each of 4 waves/block owns a 32-col slice
// (small reg footprint, no spills); cross-col exchanges via 13KB LDS.

typedef unsigned short u16;
typedef __attribute__((ext_vector_type(4))) float f32x4;
typedef __attribute__((ext_vector_type(8))) short bf16x8;

#define DI static __device__ __forceinline__

DI u16 f2bf(float f) {
    unsigned u = __builtin_bit_cast(unsigned, f);
    return (u16)((u + 0x7fffu + ((u >> 16) & 1u)) >> 16);  // RNE
}

DI bf16x8 cvt8(float4 a, float4 b) {
    u16 tmp[8] = {f2bf(a.x), f2bf(a.y), f2bf(a.z), f2bf(a.w),
                  f2bf(b.x), f2bf(b.y), f2bf(b.z), f2bf(b.w)};
    return *(const bf16x8*)tmp;
}

// B-operand image: element (k,n) at (((k>>5)*128+n)*4 + (((k>>3)&3)^((n>>1)&3)))*8 + (k&7)
DI int imgIdx(int k, int n) {
    return (((k >> 5) * 128 + n) * 4 + (((k >> 3) & 3) ^ ((n >> 1) & 3))) * 8 + (k & 7);
}
// B fragment (16B) direct from a weight/edge image in global memory.
DI bf16x8 wfragG(const u16* __restrict__ img, int kc, int tt, int l15, int quad) {
    return *(const bf16x8*)&img[(((kc * 128 + tt * 16 + l15) * 4) + (quad ^ ((l15 >> 1) & 3))) * 8];
}

#define MFMA16(a, b, c) __builtin_amdgcn_mfma_f32_16x16x32_bf16(a, b, c, 0, 0, 0)

// ---------------------------------------------------------------- prep 1
__global__ __launch_bounds__(256) void k_prep1(
    const float* __restrict__ linkW, const float* __restrict__ resetW,
    const float* __restrict__ updateW, const float* __restrict__ transW,
    const float* __restrict__ attW1, const float* __restrict__ outW,
    float* __restrict__ W2, u16* __restrict__ linkImg, u16* __restrict__ WrImg,
    u16* __restrict__ WzImg, u16* __restrict__ WhImg, u16* __restrict__ attW1Img,
    u16* __restrict__ outWImg)
{
    int blk = blockIdx.x, t = threadIdx.x;
    if (blk < 256) {
        int idx = blk * 256 + t;
        int out = idx >> 2, q = idx & 3;
        int r = out >> 7, c = out & 127;
        const float* ar = linkW + r * 128 + q * 32;
        float acc = 0.f;
#pragma unroll
        for (int k = 0; k < 32; k++) acc += ar[k] * linkW[(q * 32 + k) * 128 + c];
        acc += __shfl_xor(acc, 1);
        acc += __shfl_xor(acc, 2);
        if (q == 0) W2[out] = acc;
    } else {
        const float* src; u16* dst; int base;
        if (blk < 260)      { src = resetW;  dst = WrImg;    base = 256; }
        else if (blk < 264) { src = updateW; dst = WzImg;    base = 260; }
        else if (blk < 268) { src = transW;  dst = WhImg;    base = 264; }
        else if (blk < 270) { src = linkW;   dst = linkImg;  base = 268; }
        else if (blk < 272) { src = attW1;   dst = attW1Img; base = 270; }
        else                { src = outW;    dst = outWImg;  base = 272; }
        int off = (blk - base) * 8192;
        for (int i = 0; i < 32; i++) {
            int e = off + t + i * 256;
            int k = e >> 7, n = e & 127;
            dst[imgIdx(k, n)] = f2bf(src[e]);
        }
    }
}

// ---------------------------------------------------------------- prep 2
__global__ __launch_bounds__(256) void k_prep2(
    const float* __restrict__ linkW, const float* __restrict__ linkb,
    const float* __restrict__ W2, u16* __restrict__ W3Img, float* __restrict__ ebias)
{
    int blk = blockIdx.x, t = threadIdx.x;
    if (blk < 256) {
        int idx = blk * 256 + t;
        int out = idx >> 2, q = idx & 3;
        int r = out >> 7, c = out & 127;
        const float* ar = W2 + r * 128 + q * 32;
        float acc = 0.f;
#pragma unroll
        for (int k = 0; k < 32; k++) acc += ar[k] * linkW[(q * 32 + k) * 128 + c];
        acc += __shfl_xor(acc, 1);
        acc += __shfl_xor(acc, 2);
        if (q == 0) W3Img[imgIdx(r, c)] = f2bf(acc);
    } else if (t < 128) {
        float acc = linkb[t];
#pragma unroll 8
        for (int k = 0; k < 128; k++) acc += linkb[k] * (W2[k * 128 + t] + linkW[k * 128 + t]);
        ebias[t] = acc;
    }
}

// ---------------------------------------------------------------- E transpose (+edge resid)
__global__ __launch_bounds__(256) void k_te(
    const float* __restrict__ E0, u16* __restrict__ Eswz, float* __restrict__ resid)
{
    __shared__ alignas(16) u16 sT[4096];
    __shared__ float sCol[128];
    int t = threadIdx.x, kc = blockIdx.x, b = blockIdx.y;
    const float* Eb = E0 + (size_t)b * 262144 + (size_t)kc * 32 * 128;
    if (t < 128) sCol[t] = 0.f;
    float part[4] = {0.f, 0.f, 0.f, 0.f};
    int ncol = (t & 31) * 4;
    for (int i = 0; i < 4; i++) {
        int f4i = t + i * 256;
        int k5 = f4i >> 5;
        float4 v = *(const float4*)&Eb[k5 * 128 + ncol];
        int g = k5 >> 3, o = k5 & 7;
        float vv[4] = {v.x, v.y, v.z, v.w};
#pragma unroll
        for (int j = 0; j < 4; j++) {
            int n = ncol + j;
            sT[(n * 4 + (g ^ ((n >> 1) & 3))) * 8 + o] = f2bf(vv[j]);
            part[j] += vv[j];
        }
    }
    __syncthreads();
#pragma unroll
    for (int j = 0; j < 4; j++) atomicAdd(&sCol[ncol + j], part[j]);
    u16* dst = Eswz + (size_t)b * 262144 + (size_t)kc * 4096;
    ((uint4*)dst)[t] = ((const uint4*)sT)[t];
    ((uint4*)dst)[t + 256] = ((const uint4*)sT)[t + 256];
    __syncthreads();
    if (t < 128) atomicAdd(&resid[b * 128 + t], sCol[t]);
}

// ---------------------------------------------------------------- G0 = A @ E0  (+rowsum(A))
__global__ __launch_bounds__(256, 3) void k_g0(
    const float* __restrict__ A, const u16* __restrict__ Eswz,
    u16* __restrict__ aOut, float* __restrict__ rowsum)
{
    __shared__ float sAcc[4][16][128];
    __shared__ float sRs[4][16];
    int t = threadIdx.x, wid = t >> 6, lane = t & 63, l15 = lane & 15, quad = lane >> 4;
    int bx = blockIdx.x;
    int g = bx >> 8, rmod = bx & 255;
    int b = (rmod & 7) + 8 * g;
    int s = (rmod >> 3) & 31;
    size_t r0 = (size_t)b * 512 + (size_t)s * 16;
    const u16* Eb = Eswz + (size_t)b * 262144;
    const float* Ar = A + (r0 + l15) * 2048;
    int kbase = wid * 16;

    f32x4 acc[8];
#pragma unroll
    for (int i = 0; i < 8; i++) acc[i] = (f32x4){0.f, 0.f, 0.f, 0.f};
    float rsum = 0.f;

    float4 xc = *(const float4*)&Ar[kbase * 32 + quad * 8];
    float4 yc = *(const float4*)&Ar[kbase * 32 + quad * 8 + 4];
    bf16x8 bc[8];
#pragma unroll
    for (int tt = 0; tt < 8; tt++) bc[tt] = wfragG(Eb, kbase, tt, l15, quad);

    for (int kc = 0; kc < 16; kc++) {
        int kg = kbase + kc;
        float4 xn, yn; bf16x8 bn[8];
        if (kc < 15) {
            xn = *(const float4*)&Ar[(kg + 1) * 32 + quad * 8];
            yn = *(const float4*)&Ar[(kg + 1) * 32 + quad * 8 + 4];
#pragma unroll
            for (int tt = 0; tt < 8; tt++) bn[tt] = wfragG(Eb, kg + 1, tt, l15, quad);
        }
        rsum += xc.x + xc.y + xc.z + xc.w + yc.x + yc.y + yc.z + yc.w;
        bf16x8 af = cvt8(xc, yc);
#pragma unroll
        for (int tt = 0; tt < 8; tt++) acc[tt] = MFMA16(af, bc[tt], acc[tt]);
        if (kc < 15) {
            xc = xn; yc = yn;
#pragma unroll
            for (int tt = 0; tt < 8; tt++) bc[tt] = bn[tt];
        }
    }
    rsum += __shfl_xor(rsum, 16);
    rsum += __shfl_xor(rsum, 32);
    if (quad == 0) sRs[wid][l15] = rsum;
#pragma unroll
    for (int tt = 0; tt < 8; tt++)
#pragma unroll
        for (int r = 0; r < 4; r++)
            sAcc[wid][quad * 4 + r][tt * 16 + l15] = acc[tt][r];
    __syncthreads();
    {
        int row = t >> 4, c8 = (t & 15) * 8;
        u16 o[8];
#pragma unroll
        for (int j = 0; j < 8; j++) {
            float v = sAcc[0][row][c8 + j] + sAcc[1][row][c8 + j] +
                      sAcc[2][row][c8 + j] + sAcc[3][row][c8 + j];
            o[j] = f2bf(v);
        }
        *(uint4*)&aOut[(r0 + row) * 128 + c8] = *(const uint4*)o;
    }
    if (t < 16)
        rowsum[r0 + t] = sRs[0][t] + sRs[1][t] + sRs[2][t] + sRs[3][t];
}

// ---------------------------------------------------------------- ALL 3 GRU steps + attention
// Row-local recurrence: block = 16 rows, 4 waves; wave owns 32 output cols.
// a/p never touch global between steps. LDS exchanges for full-K A-operands.
__global__ __launch_bounds__(256) void k_steps(
    const u16* __restrict__ aBuf0, const float* __restrict__ p0,
    const float* __restrict__ rowsum,
    const u16* __restrict__ linkImg, const u16* __restrict__ WrImg,
    const u16* __restrict__ WzImg, const u16* __restrict__ WhImg,
    const u16* __restrict__ attW1Img, const u16* __restrict__ outWImg,
    const float* __restrict__ link_b, const float* __restrict__ reset_b,
    const float* __restrict__ update_b, const float* __restrict__ trans_b,
    const float* __restrict__ att_b1, const float* __restrict__ att_W2,
    const float* __restrict__ att_b2, const float* __restrict__ out_b,
    float* __restrict__ atten, float* __restrict__ outPool,
    float* __restrict__ resid)
{
    __shared__ alignas(16) u16 sA[16 * 136], sRP[16 * 136], sP[16 * 136];
    __shared__ float sRed[16];
    int t = threadIdx.x, wave = t >> 6, lane = t & 63, l15 = lane & 15, quad = lane >> 4;
    size_t r0 = (size_t)blockIdx.x * 16;
    int bb = blockIdx.x >> 5;                      // batch (for resid)
    int ttA = wave * 2, ttB = wave * 2 + 1;        // this wave's column fragments
    int colA = ttA * 16 + l15, colB = ttB * 16 + l15;
    if (t < 16) sRed[t] = 0.f;

    // full-K A-operand fragments of a (=G0) and p0
    bf16x8 aF[4], pF[4];
#pragma unroll
    for (int kc = 0; kc < 4; kc++) {
        aF[kc] = *(const bf16x8*)&aBuf0[(r0 + l15) * 128 + kc * 32 + quad * 8];
        float4 x = *(const float4*)&p0[(r0 + l15) * 128 + kc * 32 + quad * 8];
        float4 y = *(const float4*)&p0[(r0 + l15) * 128 + kc * 32 + quad * 8 + 4];
        pF[kc] = cvt8(x, y);
    }
    // own-col fp32 p state (C layout: rows quad*4+r)
    f32x4 pS[2];
#pragma unroll
    for (int j = 0; j < 2; j++)
#pragma unroll
        for (int r = 0; r < 4; r++)
            pS[j][r] = p0[(r0 + quad * 4 + r) * 128 + (wave * 2 + j) * 16 + l15];
    // node part of the residual: sum over this block's 16 rows, own cols
    {
        float s0 = pS[0][0] + pS[0][1] + pS[0][2] + pS[0][3];
        float s1 = pS[1][0] + pS[1][1] + pS[1][2] + pS[1][3];
        s0 += __shfl_xor(s0, 16); s0 += __shfl_xor(s0, 32);
        s1 += __shfl_xor(s1, 16); s1 += __shfl_xor(s1, 32);
        if (quad == 0) {
            atomicAdd(&resid[bb * 128 + colA], s0);
            atomicAdd(&resid[bb * 128 + colB], s1);
        }
    }
    float sv[4];
#pragma unroll
    for (int r = 0; r < 4; r++) sv[r] = rowsum[r0 + quad * 4 + r];
    float lbA = link_b[colA], lbB = link_b[colB];
    float rbA = reset_b[colA], rbB = reset_b[colB];
    float ubA = update_b[colA], ubB = update_b[colB];
    float tbA = trans_b[colA], tbB = trans_b[colB];

    f32x4 zero4 = {0.f, 0.f, 0.f, 0.f};
    for (int step = 0; step < 3; step++) {
        // ---- phase 1: a_new (own cols) = a @ linkW + rowsum*link_b
        f32x4 cA = zero4, cB = zero4;
#pragma unroll
        for (int kc = 0; kc < 4; kc++) {
            cA = MFMA16(aF[kc], wfragG(linkImg, kc, ttA, l15, quad), cA);
            cB = MFMA16(aF[kc], wfragG(linkImg, kc, ttB, l15, quad), cB);
        }
#pragma unroll
        for (int r = 0; r < 4; r++) {
            sA[(quad * 4 + r) * 136 + colA] = f2bf(cA[r] + sv[r] * lbA);
            sA[(quad * 4 + r) * 136 + colB] = f2bf(cB[r] + sv[r] * lbB);
        }
        __syncthreads();
#pragma unroll
        for (int kc = 0; kc < 4; kc++)
            aF[kc] = *(const bf16x8*)&sA[l15 * 136 + kc * 32 + quad * 8];
        // ---- phase 2: r, z (own cols), K=256 over [a_new, p]
        f32x4 rA = zero4, rB = zero4, zA = zero4, zB = zero4;
#pragma unroll
        for (int kc = 0; kc < 8; kc++) {
            bf16x8 af = (kc < 4) ? aF[kc] : pF[kc - 4];
            rA = MFMA16(af, wfragG(WrImg, kc, ttA, l15, quad), rA);
            rB = MFMA16(af, wfragG(WrImg, kc, ttB, l15, quad), rB);
            zA = MFMA16(af, wfragG(WzImg, kc, ttA, l15, quad), zA);
            zB = MFMA16(af, wfragG(WzImg, kc, ttB, l15, quad), zB);
        }
#pragma unroll
        for (int r = 0; r < 4; r++) {
            float rvA = 1.f / (1.f + __expf(-(rA[r] + rbA)));
            float rvB = 1.f / (1.f + __expf(-(rB[r] + rbB)));
            zA[r] = 1.f / (1.f + __expf(-(zA[r] + ubA)));
            zB[r] = 1.f / (1.f + __expf(-(zB[r] + ubB)));
            sRP[(quad * 4 + r) * 136 + colA] = f2bf(rvA * pS[0][r]);
            sRP[(quad * 4 + r) * 136 + colB] = f2bf(rvB * pS[1][r]);
        }
        __syncthreads();
        bf16x8 rpF[4];
#pragma unroll
        for (int kc = 0; kc < 4; kc++)
            rpF[kc] = *(const bf16x8*)&sRP[l15 * 136 + kc * 32 + quad * 8];
        // ---- phase 3: h (own cols); GRU update (fp32 p state in regs)
        f32x4 hA = zero4, hB = zero4;
#pragma unroll
        for (int kc = 0; kc < 8; kc++) {
            bf16x8 af = (kc < 4) ? aF[kc] : rpF[kc - 4];
            hA = MFMA16(af, wfragG(WhImg, kc, ttA, l15, quad), hA);
            hB = MFMA16(af, wfragG(WhImg, kc, ttB, l15, quad), hB);
        }
#pragma unroll
        for (int r = 0; r < 4; r++) {
            float h1 = tanhf(hA[r] + tbA), h2 = tanhf(hB[r] + tbB);
            pS[0][r] = (1.f - zA[r]) * pS[0][r] + zA[r] * h1;
            pS[1][r] = (1.f - zB[r]) * pS[1][r] + zB[r] * h2;
            sP[(quad * 4 + r) * 136 + colA] = f2bf(pS[0][r]);
            sP[(quad * 4 + r) * 136 + colB] = f2bf(pS[1][r]);
        }
        __syncthreads();
#pragma unroll
        for (int kc = 0; kc < 4; kc++)
            pF[kc] = *(const bf16x8*)&sP[l15 * 136 + kc * 32 + quad * 8];
    }
    // ---- attention + out (own cols), A-operand = p3 fragments
    f32x4 atA = zero4, atB = zero4, oA = zero4, oB = zero4;
#pragma unroll
    for (int kc = 0; kc < 4; kc++) {
        atA = MFMA16(pF[kc], wfragG(attW1Img, kc, ttA, l15, quad), atA);
        atB = MFMA16(pF[kc], wfragG(attW1Img, kc, ttB, l15, quad), atB);
        oA  = MFMA16(pF[kc], wfragG(outWImg,  kc, ttA, l15, quad), oA);
        oB  = MFMA16(pF[kc], wfragG(outWImg,  kc, ttB, l15, quad), oB);
    }
    float b1A = att_b1[colA], b1B = att_b1[colB];
    float w2A = att_W2[colA], w2B = att_W2[colB];
    float obA = out_b[colA],  obB = out_b[colB];
    float pr[4];
#pragma unroll
    for (int r = 0; r < 4; r++) {
        pr[r] = tanhf(atA[r] + b1A) * w2A + tanhf(atB[r] + b1B) * w2B;
        outPool[(r0 + quad * 4 + r) * 128 + colA] = tanhf(oA[r] + obA);
        outPool[(r0 + quad * 4 + r) * 128 + colB] = tanhf(oB[r] + obB);
    }
#pragma unroll
    for (int r = 0; r < 4; r++) {
        float v = pr[r];
        v += __shfl_xor(v, 1); v += __shfl_xor(v, 2);
        v += __shfl_xor(v, 4); v += __shfl_xor(v, 8);
        if (l15 == 0) atomicAdd(&sRed[quad * 4 + r], v);
    }
    __syncthreads();
    if (t < 16) atten[r0 + t] = sRed[t] + att_b2[0];
}

// ---------------------------------------------------------------- edges out: E0@W3 + ebias
__global__ __launch_bounds__(64) void k_eout(
    const float* __restrict__ E0, const u16* __restrict__ W3Img,
    const float* __restrict__ ebias, float* __restrict__ Eout)
{
    int t = threadIdx.x, l15 = t & 15, quad = t >> 4;
    size_t r0 = (size_t)blockIdx.x * 16;
    bf16x8 eF[4];
#pragma unroll
    for (int kc = 0; kc < 4; kc++) {
        float4 x = *(const float4*)&E0[(r0 + l15) * 128 + kc * 32 + quad * 8];
        float4 y = *(const float4*)&E0[(r0 + l15) * 128 + kc * 32 + quad * 8 + 4];
        eF[kc] = cvt8(x, y);
    }
    f32x4 acc[8];
#pragma unroll
    for (int i = 0; i < 8; i++) acc[i] = (f32x4){0.f, 0.f, 0.f, 0.f};
    {
        bf16x8 wc[8], wn[8];
#pragma unroll
        for (int tt = 0; tt < 8; tt++) wc[tt] = wfragG(W3Img, 0, tt, l15, quad);
#pragma unroll
        for (int kc = 0; kc < 4; kc++) {
            if (kc < 3)
#pragma unroll
                for (int tt = 0; tt < 8; tt++) wn[tt] = wfragG(W3Img, kc + 1, tt, l15, quad);
#pragma unroll
            for (int tt = 0; tt < 8; tt++) acc[tt] = MFMA16(eF[kc], wc[tt], acc[tt]);
            if (kc < 3)
#pragma unroll
                for (int tt = 0; tt < 8; tt++) wc[tt] = wn[tt];
        }
    }
#pragma unroll
    for (int tt = 0; tt < 8; tt++) {
        int col = tt * 16 + l15; float eb = ebias[col];
#pragma unroll
        for (int r = 0; r < 4; r++)
            Eout[(r0 + quad * 4 + r) * 128 + col] = acc[tt][r] + eb;
    }
}

// ---------------------------------------------------------------- softmax-pool + residual
__global__ __launch_bounds__(512) void k_fin(
    const float* __restrict__ atten, const float* __restrict__ outPool,
    const float* __restrict__ resid,
    float* __restrict__ outRes, float* __restrict__ outMul)
{
    __shared__ float swv[512];
    __shared__ float sred[512];
    __shared__ float sacc[4][128];
    int t = threadIdx.x, b = blockIdx.x;
    float a = atten[b * 512 + t];
    sred[t] = a; __syncthreads();
    for (int s = 256; s > 0; s >>= 1) { if (t < s) sred[t] = fmaxf(sred[t], sred[t + s]); __syncthreads(); }
    float mx = sred[0]; __syncthreads();
    float e = __expf(a - mx);
    swv[t] = e; sred[t] = e; __syncthreads();
    for (int s = 256; s > 0; s >>= 1) { if (t < s) sred[t] += sred[t + s]; __syncthreads(); }
    float Z = sred[0]; __syncthreads();
    int col = t & 127, q = t >> 7;
    const float* op = outPool + ((size_t)b * 512 + q * 128) * 128 + col;
    float accM = 0.f;
    for (int n = 0; n < 128; n++) accM += swv[q * 128 + n] * op[(size_t)n * 128];
    sacc[q][col] = accM;
    __syncthreads();
    if (t < 128) {
        float mulv = (sacc[0][t] + sacc[1][t] + sacc[2][t] + sacc[3][t]) / Z;
        float rv = resid[b * 128 + t] * (1.f / 2560.f);
        outMul[b * 128 + t] = mulv;
        outRes[b * 128 + t] = fmaxf(0.f, tanhf(mulv) + rv);
    }
}

// ================================================================ launch
extern "C" void kernel_launch(void* const* d_in, const int* in_sizes, int n_in,
                              void* d_out, int out_size, void* d_ws, size_t ws_size,
                              hipStream_t stream)
{
    const float* prop0  = (const float*)d_in[0];
    const float* edge0  = (const float*)d_in[1];
    const float* Amat   = (const float*)d_in[2];
    const float* linkW  = (const float*)d_in[4];
    const float* linkb  = (const float*)d_in[5];
    const float* resetW = (const float*)d_in[6];
    const float* resetb = (const float*)d_in[7];
    const float* updateW= (const float*)d_in[8];
    const float* updateb= (const float*)d_in[9];
    const float* transW = (const float*)d_in[10];
    const float* transb = (const float*)d_in[11];
    const float* attW1  = (const float*)d_in[12];
    const float* attb1  = (const float*)d_in[13];
    const float* attW2  = (const float*)d_in[14];
    const float* attb2  = (const float*)d_in[15];
    const float* outW   = (const float*)d_in[16];
    const float* outb   = (const float*)d_in[17];

    char* w = (char*)d_ws;
    u16*   ws_a_bf    = (u16*)(w);                    // 4,194,304 B
    float* ws_rowsum  = (float*)(w + 4194304);        //    65,536 B
    float* ws_atten   = (float*)(w + 4259840);        //    65,536 B
    float* ws_resid   = (float*)(w + 4325376);        //    16,384 B
    float* ws_W2      = (float*)(w + 4341760);        //    65,536 B
    float* ws_ebias   = (float*)(w + 4407296);        //       512 B
    u16*   ws_linkImg = (u16*)(w + 4407808);          //    32,768 B
    u16*   ws_W3Img   = (u16*)(w + 4440576);          //    32,768 B
    u16*   ws_WrImg   = (u16*)(w + 4473344);          //    65,536 B
    u16*   ws_WzImg   = (u16*)(w + 4538880);          //    65,536 B
    u16*   ws_WhImg   = (u16*)(w + 4604416);          //    65,536 B
    u16*   ws_attW1Img= (u16*)(w + 4669952);          //    32,768 B
    u16*   ws_outWImg = (u16*)(w + 4702720);          //    32,768 B (~4.7 MB)

    float* out_res  = (float*)d_out;
    float* out_mul  = out_res + 4096;
    float* out_edge = out_res + 8192;
    // Scratch inside d_out edge region (dead until k_eout, which runs last):
    u16*   Eswz     = (u16*)out_edge;                 // 16.78 MB
    float* outPool  = out_edge + 4194304;             // next 8.39 MB

    hipMemsetAsync(ws_resid, 0, 32 * 128 * sizeof(float), stream);
    k_prep1<<<274, 256, 0, stream>>>(linkW, resetW, updateW, transW, attW1, outW,
                                     ws_W2, ws_linkImg, ws_WrImg, ws_WzImg, ws_WhImg,
                                     ws_attW1Img, ws_outWImg);
    k_prep2<<<257, 256, 0, stream>>>(linkW, linkb, ws_W2, ws_W3Img, ws_ebias);
    k_te<<<dim3(64, 32), 256, 0, stream>>>(edge0, Eswz, ws_resid);
    k_g0<<<1024, 256, 0, stream>>>(Amat, Eswz, ws_a_bf, ws_rowsum);
    k_steps<<<1024, 256, 0, stream>>>(ws_a_bf, prop0, ws_rowsum,
                                      ws_linkImg, ws_WrImg, ws_WzImg, ws_WhImg,
                                      ws_attW1Img, ws_outWImg,
                                      linkb, resetb, updateb, transb,
                                      attb1, attW2, attb2, outb,
                                      ws_atten, outPool, ws_resid);
    k_fin<<<32, 512, 0, stream>>>(ws_atten, outPool, ws_resid, out_res, out_mul);
    k_eout<<<4096, 64, 0, stream>>>(edge0, ws_W3Img, ws_ebias, out_edge);
}